// Round 3
// baseline (6586.900 us; speedup 1.0000x reference)
//
#include <hip/hip_runtime.h>
#include <hip/hip_bf16.h>
#include <math.h>

#define BB 512
#define SS 128
#define DD 256
#define HH 4
#define TOPK 8
#define D3 768
#define DMA 248
#define ACT_ 8

// ---------------------------------------------------------------------------
// K1: xa = [ tanh(x_obs@W1+b1)@W2 + b2 , a_prev ]   (16 tokens per block)
// ---------------------------------------------------------------------------
__global__ void k_xa(const float* __restrict__ x_obs, const float* __restrict__ a_prev,
                     const float* __restrict__ W1, const float* __restrict__ b1,
                     const float* __restrict__ W2, const float* __restrict__ b2,
                     float* __restrict__ xa) {
    __shared__ float xsh[16][64];
    __shared__ float hsh[16][256];
    const int t0 = blockIdx.x * 16;
    const int tid = threadIdx.x;

    for (int i = tid; i < 16 * 64; i += 256) {
        int t = i >> 6, c = i & 63;
        xsh[t][c] = x_obs[(size_t)(t0 + t) * 64 + c];
    }
    __syncthreads();

    float acc[16];
    {
        float bias = b1[tid];
#pragma unroll
        for (int t = 0; t < 16; ++t) acc[t] = bias;
        for (int k = 0; k < 64; ++k) {
            float w = W1[k * 256 + tid];
#pragma unroll
            for (int t = 0; t < 16; ++t) acc[t] = fmaf(xsh[t][k], w, acc[t]);
        }
#pragma unroll
        for (int t = 0; t < 16; ++t) hsh[t][tid] = tanhf(acc[t]);
    }
    __syncthreads();

    if (tid < DMA) {
        float bias = b2[tid];
#pragma unroll
        for (int t = 0; t < 16; ++t) acc[t] = bias;
        for (int k = 0; k < 256; ++k) {
            float w = W2[k * DMA + tid];
#pragma unroll
            for (int t = 0; t < 16; ++t) acc[t] = fmaf(hsh[t][k], w, acc[t]);
        }
#pragma unroll
        for (int t = 0; t < 16; ++t) xa[(size_t)(t0 + t) * 256 + tid] = acc[t];
    } else {
        int c = tid - DMA;
#pragma unroll
        for (int t = 0; t < 16; ++t)
            xa[(size_t)(t0 + t) * 256 + tid] = a_prev[(size_t)(t0 + t) * ACT_ + c];
    }
}

// ---------------------------------------------------------------------------
// K2: per (b,h): q_h,k_h from xa (disjoint Wqkv columns), scores in 8x8 reg
//     tiles, fp64 scaled row sums -> hsums. Never materializes scores.
// ---------------------------------------------------------------------------
__global__ void k_score(const float* __restrict__ xa, const float* __restrict__ Wqkv,
                        const float* __restrict__ bqkv, double* __restrict__ hsums) {
    __shared__ float xt[16][256];   // 16 KB: xa row tile
    __shared__ float qc[128][33];   // 16.5 KB: q d-chunk (pad 33)
    __shared__ float kc[128][33];   // 16.5 KB
    const int bh = blockIdx.x;
    const int b = bh >> 2, h = bh & 3;
    const int tid = threadIdx.x;
    const int ty = tid >> 4, tx = tid & 15;
    const float* xab = xa + (size_t)b * SS * DD;

    float acc[8][8];
#pragma unroll
    for (int r = 0; r < 8; ++r)
#pragma unroll
        for (int c = 0; c < 8; ++c) acc[r][c] = 0.f;

    for (int chunk = 0; chunk < 2; ++chunk) {
        const int c0 = chunk * 32;
        for (int rt = 0; rt < 8; ++rt) {
            __syncthreads();
#pragma unroll
            for (int t = 0; t < 16; ++t)
                xt[t][tid] = xab[(rt * 16 + t) * 256 + tid];
            __syncthreads();
#pragma unroll
            for (int j = 0; j < 2; ++j) {
                int id = j * 256 + tid;            // 0..511
                int rl = id >> 5, col = id & 31;
                float aq = bqkv[h * 64 + c0 + col];
                float ak = bqkv[256 + h * 64 + c0 + col];
                const float* wq = Wqkv + (h * 64 + c0 + col);
                const float* wk = Wqkv + (256 + h * 64 + c0 + col);
                for (int kk = 0; kk < 256; ++kk) {
                    float x = xt[rl][kk];
                    aq = fmaf(x, wq[(size_t)kk * D3], aq);
                    ak = fmaf(x, wk[(size_t)kk * D3], ak);
                }
                qc[rt * 16 + rl][col] = aq;
                kc[rt * 16 + rl][col] = ak;
            }
        }
        __syncthreads();
        for (int d = 0; d < 32; ++d) {
            float qv[8], kv[8];
#pragma unroll
            for (int r = 0; r < 8; ++r) qv[r] = qc[ty + 16 * r][d];
#pragma unroll
            for (int c = 0; c < 8; ++c) kv[c] = kc[tx + 16 * c][d];
#pragma unroll
            for (int r = 0; r < 8; ++r)
#pragma unroll
                for (int c = 0; c < 8; ++c) acc[r][c] = fmaf(qv[r], kv[c], acc[r][c]);
        }
        __syncthreads();
    }
    // scaled fp64 row sums; rows of thread: ty+16r, cols: tx+16c
#pragma unroll
    for (int r = 0; r < 8; ++r) {
        double rs = 0.0;
#pragma unroll
        for (int c = 0; c < 8; ++c) rs += (double)acc[r][c];
        rs += __shfl_xor(rs, 1);
        rs += __shfl_xor(rs, 2);
        rs += __shfl_xor(rs, 4);
        rs += __shfl_xor(rs, 8);
        if (tx == 0) hsums[(size_t)bh * SS + ty + 16 * r] = rs * 0.125;
    }
}

// ---------------------------------------------------------------------------
// K3: per-b top-8 (jax semantics: descending, ties -> lower index first)
// ---------------------------------------------------------------------------
__global__ void k_topk(const double* __restrict__ hsums, int* __restrict__ idxb) {
    __shared__ double ss[128];
    const int b = blockIdx.x;
    const int tid = threadIdx.x;
    const double* hp = hsums + (size_t)b * (HH * SS);
    ss[tid] = hp[tid] + hp[128 + tid] + hp[256 + tid] + hp[384 + tid];
    __syncthreads();
    if (tid == 0) {
        bool tk[128];
        for (int s = 0; s < 128; ++s) tk[s] = false;
        for (int t = 0; t < TOPK; ++t) {
            double best = -1e300;
            int bi = 0;
            for (int s = 0; s < 128; ++s)
                if (!tk[s] && ss[s] > best) { best = ss[s]; bi = s; }
            tk[bi] = true;
            idxb[b * TOPK + t] = bi;
        }
    }
}

// ---------------------------------------------------------------------------
// K4: per-b: recompute k_h,v_h (bf16 LDS), q for the 8 selected rows,
//     softmax, ctx, Wo -> reshaped rows straight into d_out.
// ---------------------------------------------------------------------------
__global__ void k_sel(const float* __restrict__ xa, const float* __restrict__ Wqkv,
                      const float* __restrict__ bqkv, const float* __restrict__ Wo,
                      const float* __restrict__ bo, const int* __restrict__ idxb,
                      float* __restrict__ resh_out) {
    __shared__ float xsel[8][256];             // 8 KB
    __shared__ float qsel[8][256];             // 8 KB
    __shared__ float xt[8][256];               // 8 KB
    __shared__ __hip_bfloat16 kbuf[128][66];   // 16.5 KB
    __shared__ __hip_bfloat16 vbuf[128][66];   // 16.5 KB
    __shared__ float sbuf[8][128];             // 4 KB
    __shared__ float ctxh[8][64];              // 2 KB
    __shared__ int sidx[8];
    const int b = blockIdx.x;
    const int tid = threadIdx.x;
    const float* xab = xa + (size_t)b * SS * DD;

    if (tid < 8) sidx[tid] = idxb[b * TOPK + tid];
    __syncthreads();
#pragma unroll
    for (int t = 0; t < 8; ++t) xsel[t][tid] = xab[sidx[t] * 256 + tid];
    __syncthreads();
    // qsel[8][256]: all heads at once (q cols 0..255 of Wqkv)
    {
        float a[8];
        float bq = bqkv[tid];
#pragma unroll
        for (int t = 0; t < 8; ++t) a[t] = bq;
        for (int kk = 0; kk < 256; ++kk) {
            float w = Wqkv[(size_t)kk * D3 + tid];
#pragma unroll
            for (int t = 0; t < 8; ++t) a[t] = fmaf(xsel[t][kk], w, a[t]);
        }
#pragma unroll
        for (int t = 0; t < 8; ++t) qsel[t][tid] = a[t];
    }
    float racc[8];
#pragma unroll
    for (int r = 0; r < 8; ++r) racc[r] = 0.f;

    for (int h = 0; h < 4; ++h) {
        // build k_h, v_h (bf16) via 16 row-tiles of 8
        for (int rt = 0; rt < 16; ++rt) {
            __syncthreads();
#pragma unroll
            for (int t = 0; t < 8; ++t) xt[t][tid] = xab[(rt * 8 + t) * 256 + tid];
            __syncthreads();
#pragma unroll
            for (int j = 0; j < 4; ++j) {
                int id = j * 256 + tid;                 // 0..1023
                int kind = id >> 9, rl = (id >> 6) & 7, col = id & 63;
                int wc = (kind ? 512 : 256) + h * 64 + col;
                float a = bqkv[wc];
                const float* wp = Wqkv + wc;
                for (int kk = 0; kk < 256; ++kk)
                    a = fmaf(xt[rl][kk], wp[(size_t)kk * D3], a);
                if (kind) vbuf[rt * 8 + rl][col] = __float2bfloat16(a);
                else      kbuf[rt * 8 + rl][col] = __float2bfloat16(a);
            }
        }
        __syncthreads();
        // scores 8x128 (scaled)
#pragma unroll
        for (int j = 0; j < 4; ++j) {
            int id = j * 256 + tid;
            int row = id >> 7, col = id & 127;
            float s = 0.f;
            for (int d = 0; d < 64; ++d)
                s = fmaf(qsel[row][h * 64 + d], __bfloat162float(kbuf[col][d]), s);
            sbuf[row][col] = s * 0.125f;
        }
        __syncthreads();
        // softmax (8 serial rows; cheap)
        if (tid < 8) {
            float m = -3.4e38f;
            for (int k2 = 0; k2 < 128; ++k2) m = fmaxf(m, sbuf[tid][k2]);
            float ssum = 0.f;
            for (int k2 = 0; k2 < 128; ++k2) {
                float e = __expf(sbuf[tid][k2] - m);
                sbuf[tid][k2] = e;
                ssum += e;
            }
            float inv = 1.f / ssum;
            for (int k2 = 0; k2 < 128; ++k2) sbuf[tid][k2] *= inv;
        }
        __syncthreads();
        // ctx 8x64
#pragma unroll
        for (int j = 0; j < 2; ++j) {
            int id = j * 256 + tid;
            int row = id >> 6, col = id & 63;
            float c = 0.f;
            for (int k2 = 0; k2 < 128; ++k2)
                c = fmaf(sbuf[row][k2], __bfloat162float(vbuf[k2][col]), c);
            ctxh[row][col] = c;
        }
        __syncthreads();
        // trans_out accumulation: col = tid
        for (int jj = 0; jj < 64; ++jj) {
            float w = Wo[(size_t)(h * 64 + jj) * 256 + tid];
#pragma unroll
            for (int r = 0; r < 8; ++r) racc[r] = fmaf(ctxh[r][jj], w, racc[r]);
        }
        __syncthreads();
    }
    float bov = bo[tid];
#pragma unroll
    for (int r = 0; r < 8; ++r)
        resh_out[(size_t)b * 2048 + r * 256 + tid] = racc[r] + bov;
}

// ---------------------------------------------------------------------------
// K5: GRUCell. reshaped read back from d_out. 4 batch rows per block.
// ---------------------------------------------------------------------------
__global__ void k_gru(const float* __restrict__ resh_in, const float* __restrict__ prev_d,
                      const float* __restrict__ W_ih, const float* __restrict__ b_ih,
                      const float* __restrict__ W_hh, const float* __restrict__ b_hh,
                      float* __restrict__ newd) {
    __shared__ float resh[4][2048];
    __shared__ float pd[4][256];
    const int b0 = blockIdx.x * 4;
    const int tid = threadIdx.x;

    for (int bb = 0; bb < 4; ++bb) {
#pragma unroll
        for (int t = 0; t < 8; ++t)
            resh[bb][t * 256 + tid] = resh_in[(size_t)(b0 + bb) * 2048 + t * 256 + tid];
        pd[bb][tid] = prev_d[(size_t)(b0 + bb) * 256 + tid];
    }
    __syncthreads();

    float ir[4], iz[4], inn[4], hr[4], hz[4], hn[4];
    {
        float bi0 = b_ih[tid], bi1 = b_ih[256 + tid], bi2 = b_ih[512 + tid];
        float bh0 = b_hh[tid], bh1 = b_hh[256 + tid], bh2 = b_hh[512 + tid];
#pragma unroll
        for (int bb = 0; bb < 4; ++bb) {
            ir[bb] = bi0; iz[bb] = bi1; inn[bb] = bi2;
            hr[bb] = bh0; hz[bb] = bh1; hn[bb] = bh2;
        }
    }
    for (int k = 0; k < 2048; ++k) {
        const float* wr = W_ih + (size_t)k * D3;
        float w0 = wr[tid], w1 = wr[256 + tid], w2 = wr[512 + tid];
#pragma unroll
        for (int bb = 0; bb < 4; ++bb) {
            float x = resh[bb][k];
            ir[bb] = fmaf(x, w0, ir[bb]);
            iz[bb] = fmaf(x, w1, iz[bb]);
            inn[bb] = fmaf(x, w2, inn[bb]);
        }
    }
    for (int k = 0; k < 256; ++k) {
        const float* wr = W_hh + (size_t)k * D3;
        float w0 = wr[tid], w1 = wr[256 + tid], w2 = wr[512 + tid];
#pragma unroll
        for (int bb = 0; bb < 4; ++bb) {
            float x = pd[bb][k];
            hr[bb] = fmaf(x, w0, hr[bb]);
            hz[bb] = fmaf(x, w1, hz[bb]);
            hn[bb] = fmaf(x, w2, hn[bb]);
        }
    }
#pragma unroll
    for (int bb = 0; bb < 4; ++bb) {
        float r = 1.f / (1.f + __expf(-(ir[bb] + hr[bb])));
        float z = 1.f / (1.f + __expf(-(iz[bb] + hz[bb])));
        float n = tanhf(inn[bb] + r * hn[bb]);
        newd[(size_t)(b0 + bb) * 256 + tid] = (1.f - z) * n + z * pd[bb][tid];
    }
}

// ---------------------------------------------------------------------------
extern "C" void kernel_launch(void* const* d_in, const int* in_sizes, int n_in,
                              void* d_out, int out_size, void* d_ws, size_t ws_size,
                              hipStream_t stream) {
    const float* prev_d = (const float*)d_in[0];
    const float* x_obs  = (const float*)d_in[1];
    const float* a_prev = (const float*)d_in[2];
    const float* W1     = (const float*)d_in[3];
    const float* b1     = (const float*)d_in[4];
    const float* W2     = (const float*)d_in[5];
    const float* b2     = (const float*)d_in[6];
    const float* Wqkv   = (const float*)d_in[7];
    const float* bqkv   = (const float*)d_in[8];
    const float* Wo     = (const float*)d_in[9];
    const float* bo     = (const float*)d_in[10];
    const float* W_ih   = (const float*)d_in[11];
    const float* b_ih   = (const float*)d_in[12];
    const float* W_hh   = (const float*)d_in[13];
    const float* b_hh   = (const float*)d_in[14];
    float* out = (float*)d_out;

    // ws: xa fp32 (64 MiB) | hsums fp64 (2 MiB) | idx (16 KiB)  => ~66 MiB
    float* xa = (float*)d_ws;
    double* hsums = (double*)((char*)d_ws + (size_t)BB * SS * DD * 4);
    int* idxb = (int*)((char*)hsums + (size_t)BB * HH * SS * 8);

    float* newd = out;                       // [B, D]
    float* resh = out + (size_t)BB * DD;     // [B, TOPK*D]

    k_xa   <<<(BB * SS) / 16, 256, 0, stream>>>(x_obs, a_prev, W1, b1, W2, b2, xa);
    k_score<<<BB * HH, 256, 0, stream>>>(xa, Wqkv, bqkv, hsums);
    k_topk <<<BB, 128, 0, stream>>>(hsums, idxb);
    k_sel  <<<BB, 256, 0, stream>>>(xa, Wqkv, bqkv, Wo, bo, idxb, resh);
    k_gru  <<<BB / 4, 256, 0, stream>>>(resh, prev_d, W_ih, b_ih, W_hh, b_hh, newd);
}

// Round 4
// 1118.059 us; speedup vs baseline: 5.8914x; 5.8914x over previous
//
#include <hip/hip_runtime.h>
#include <hip/hip_bf16.h>
#include <math.h>

#define BB 512
#define SS 128
#define DD 256
#define HH 4
#define TOPK 8
#define D3 768
#define DMA 248
#define ACT_ 8

// ---------------------------------------------------------------------------
// K1: xa = [ tanh(x_obs@W1+b1)@W2 + b2 , a_prev ]   (16 tokens per block)
// ---------------------------------------------------------------------------
__global__ void k_xa(const float* __restrict__ x_obs, const float* __restrict__ a_prev,
                     const float* __restrict__ W1, const float* __restrict__ b1,
                     const float* __restrict__ W2, const float* __restrict__ b2,
                     float* __restrict__ xa) {
    __shared__ float xsh[16][64];
    __shared__ float hsh[16][256];
    const int t0 = blockIdx.x * 16;
    const int tid = threadIdx.x;

    for (int i = tid; i < 16 * 64; i += 256) {
        int t = i >> 6, c = i & 63;
        xsh[t][c] = x_obs[(size_t)(t0 + t) * 64 + c];
    }
    __syncthreads();

    float acc[16];
    {
        float bias = b1[tid];
#pragma unroll
        for (int t = 0; t < 16; ++t) acc[t] = bias;
        for (int k = 0; k < 64; ++k) {
            float w = W1[k * 256 + tid];
#pragma unroll
            for (int t = 0; t < 16; ++t) acc[t] = fmaf(xsh[t][k], w, acc[t]);
        }
#pragma unroll
        for (int t = 0; t < 16; ++t) hsh[t][tid] = tanhf(acc[t]);
    }
    __syncthreads();

    if (tid < DMA) {
        float bias = b2[tid];
#pragma unroll
        for (int t = 0; t < 16; ++t) acc[t] = bias;
        for (int k = 0; k < 256; ++k) {
            float w = W2[k * DMA + tid];
#pragma unroll
            for (int t = 0; t < 16; ++t) acc[t] = fmaf(hsh[t][k], w, acc[t]);
        }
#pragma unroll
        for (int t = 0; t < 16; ++t) xa[(size_t)(t0 + t) * 256 + tid] = acc[t];
    } else {
        int c = tid - DMA;
#pragma unroll
        for (int t = 0; t < 16; ++t)
            xa[(size_t)(t0 + t) * 256 + tid] = a_prev[(size_t)(t0 + t) * ACT_ + c];
    }
}

// ---------------------------------------------------------------------------
// K2: per batch b: K/V GEMM (k,v bf16 out), fp32 ksum in-register,
//     score_sum[s] = (xa[s]·(Wq@ksum) + bq·ksum)/8 (fp64), wave top-8.
// ---------------------------------------------------------------------------
__global__ void __launch_bounds__(256) k_kv(const float* __restrict__ xa,
        const float* __restrict__ Wqkv, const float* __restrict__ bqkv,
        __hip_bfloat16* __restrict__ kbf, __hip_bfloat16* __restrict__ vbf,
        int* __restrict__ idxb) {
    __shared__ float xt[256][36];   // transposed x tile [kk][token], 36 KB
    __shared__ float ksumsh[256];
    __shared__ float wqksh[256];
    __shared__ double ssd[128];
    const int b = blockIdx.x;
    const int tid = threadIdx.x;
    const float* xab = xa + (size_t)b * SS * DD;

    const float bk = bqkv[256 + tid];
    const float bv = bqkv[512 + tid];
    float ksum = 0.f;

    for (int tile = 0; tile < 4; ++tile) {
        __syncthreads();
        for (int it = 0; it < 32; ++it) {
            int id = it * 256 + tid;
            int row = id >> 8, col = id & 255;
            xt[col][row] = xab[(size_t)(tile * 32 + row) * 256 + col];
        }
        __syncthreads();
        float ak[32], av[32];
#pragma unroll
        for (int t = 0; t < 32; ++t) { ak[t] = bk; av[t] = bv; }
        for (int kk = 0; kk < 256; ++kk) {
            float w1 = Wqkv[(size_t)kk * D3 + 256 + tid];
            float w2 = Wqkv[(size_t)kk * D3 + 512 + tid];
            const float4* xp = (const float4*)&xt[kk][0];
#pragma unroll
            for (int j = 0; j < 8; ++j) {
                float4 x4 = xp[j];
                ak[j*4+0] = fmaf(x4.x, w1, ak[j*4+0]); av[j*4+0] = fmaf(x4.x, w2, av[j*4+0]);
                ak[j*4+1] = fmaf(x4.y, w1, ak[j*4+1]); av[j*4+1] = fmaf(x4.y, w2, av[j*4+1]);
                ak[j*4+2] = fmaf(x4.z, w1, ak[j*4+2]); av[j*4+2] = fmaf(x4.z, w2, av[j*4+2]);
                ak[j*4+3] = fmaf(x4.w, w1, ak[j*4+3]); av[j*4+3] = fmaf(x4.w, w2, av[j*4+3]);
            }
        }
#pragma unroll
        for (int t = 0; t < 32; ++t) {
            size_t o = ((size_t)b * SS + tile * 32 + t) * 256 + tid;
            kbf[o] = __float2bfloat16(ak[t]);
            vbf[o] = __float2bfloat16(av[t]);
            ksum += ak[t];           // deterministic order: tile asc, t asc
        }
    }
    ksumsh[tid] = ksum;
    __syncthreads();
    // wqk = Wq @ ksum (row tid of Wq); bqdot = bq . ksum
    float wq = 0.f;
    for (int col = 0; col < 256; ++col)
        wq = fmaf(Wqkv[(size_t)tid * D3 + col], ksumsh[col], wq);
    wqksh[tid] = wq;
    double bqdot = 0.0;
    for (int col = 0; col < 256; ++col)
        bqdot += (double)bqkv[col] * (double)ksumsh[col];
    __syncthreads();
    // score_sum rows: 2 threads per row, fp64
    {
        int r = tid >> 1, half = tid & 1;
        const float* xr = xab + (size_t)r * 256 + half * 128;
        const float* wk = wqksh + half * 128;
        double sd = 0.0;
        for (int d2 = 0; d2 < 128; ++d2) sd += (double)xr[d2] * (double)wk[d2];
        double so = __shfl_xor(sd, 1);
        if (half == 0) ssd[r] = (sd + so + bqdot) * 0.125;
    }
    __syncthreads();
    // wave-parallel top-8, jax semantics (descending, ties -> lower idx)
    if (tid < 64) {
        double v0 = ssd[tid], v1 = ssd[tid + 64];
        int i0 = tid, i1 = tid + 64;
        bool t0 = false, t1 = false;
        for (int t = 0; t < TOPK; ++t) {
            double c0 = t0 ? -1e300 : v0;
            double c1 = t1 ? -1e300 : v1;
            double bvv; int bi;
            if (c1 > c0) { bvv = c1; bi = i1; } else { bvv = c0; bi = i0; }
#pragma unroll
            for (int off = 1; off < 64; off <<= 1) {
                double ov = __shfl_xor(bvv, off);
                int oi = __shfl_xor(bi, off);
                if (ov > bvv || (ov == bvv && oi < bi)) { bvv = ov; bi = oi; }
            }
            if (tid == 0) idxb[b * TOPK + t] = bi;
            if (bi == i0) t0 = true;
            if (bi == i1) t1 = true;
        }
    }
}

// ---------------------------------------------------------------------------
// K3: per b: recompute q for the 8 selected rows, per-head softmax(q·k)·v,
//     Wo + bo -> reshaped rows into d_out.
// ---------------------------------------------------------------------------
__global__ void __launch_bounds__(256) k_sel(const float* __restrict__ xa,
        const float* __restrict__ Wqkv, const float* __restrict__ bqkv,
        const __hip_bfloat16* __restrict__ kbf, const __hip_bfloat16* __restrict__ vbf,
        const float* __restrict__ Wo, const float* __restrict__ bo,
        const int* __restrict__ idxb, float* __restrict__ resh_out) {
    __shared__ float xsel[8][256];            // 8 KB
    __shared__ float qsel[8][256];            // 8 KB
    __shared__ __hip_bfloat16 ksh[128][66];   // 16.5 KB
    __shared__ __hip_bfloat16 vsh[128][66];   // 16.5 KB
    __shared__ float sbuf[8][128];            // 4 KB
    __shared__ float ctxh[8][64];             // 2 KB
    __shared__ int sidx[8];
    const int b = blockIdx.x;
    const int tid = threadIdx.x;
    const float* xab = xa + (size_t)b * SS * DD;

    if (tid < 8) sidx[tid] = idxb[b * TOPK + tid];
    __syncthreads();
#pragma unroll
    for (int t = 0; t < 8; ++t) xsel[t][tid] = xab[(size_t)sidx[t] * 256 + tid];
    __syncthreads();
    {   // qsel = xsel @ Wq + bq (all heads)
        float a[8];
        float bq = bqkv[tid];
#pragma unroll
        for (int t = 0; t < 8; ++t) a[t] = bq;
        for (int kk = 0; kk < 256; ++kk) {
            float w = Wqkv[(size_t)kk * D3 + tid];
#pragma unroll
            for (int t = 0; t < 8; ++t) a[t] = fmaf(xsel[t][kk], w, a[t]);
        }
#pragma unroll
        for (int t = 0; t < 8; ++t) qsel[t][tid] = a[t];
    }
    float racc[8];
#pragma unroll
    for (int r = 0; r < 8; ++r) racc[r] = 0.f;

    for (int h = 0; h < 4; ++h) {
        __syncthreads();
        // stage k_h, v_h (bf16) tiles
        for (int it = 0; it < 32; ++it) {
            int id = it * 256 + tid;
            int row = id >> 6, col = id & 63;
            size_t g = ((size_t)b * SS + row) * 256 + h * 64 + col;
            ksh[row][col] = kbf[g];
            vsh[row][col] = vbf[g];
        }
        __syncthreads();
        // scores 8x128 (scaled)
#pragma unroll
        for (int j = 0; j < 4; ++j) {
            int id = j * 256 + tid;
            int row = id >> 7, col = id & 127;
            float s = 0.f;
            for (int d = 0; d < 64; ++d)
                s = fmaf(qsel[row][h * 64 + d], __bfloat162float(ksh[col][d]), s);
            sbuf[row][col] = s * 0.125f;
        }
        __syncthreads();
        if (tid < 8) {
            float m = -3.4e38f;
            for (int k2 = 0; k2 < 128; ++k2) m = fmaxf(m, sbuf[tid][k2]);
            float ssum = 0.f;
            for (int k2 = 0; k2 < 128; ++k2) {
                float e = __expf(sbuf[tid][k2] - m);
                sbuf[tid][k2] = e;
                ssum += e;
            }
            float inv = 1.f / ssum;
            for (int k2 = 0; k2 < 128; ++k2) sbuf[tid][k2] *= inv;
        }
        __syncthreads();
        // ctx 8x64
#pragma unroll
        for (int j = 0; j < 2; ++j) {
            int id = j * 256 + tid;
            int row = id >> 6, col = id & 63;
            float c = 0.f;
            for (int k2 = 0; k2 < 128; ++k2)
                c = fmaf(sbuf[row][k2], __bfloat162float(vsh[k2][col]), c);
            ctxh[row][col] = c;
        }
        __syncthreads();
        // trans_out accumulation (col = tid)
        for (int jj = 0; jj < 64; ++jj) {
            float w = Wo[(size_t)(h * 64 + jj) * 256 + tid];
#pragma unroll
            for (int r = 0; r < 8; ++r) racc[r] = fmaf(ctxh[r][jj], w, racc[r]);
        }
    }
    float bov = bo[tid];
#pragma unroll
    for (int r = 0; r < 8; ++r)
        resh_out[(size_t)b * 2048 + r * 256 + tid] = racc[r] + bov;
}

// ---------------------------------------------------------------------------
// K4: GRUCell. reshaped read back from d_out. 4 batch rows per block.
// ---------------------------------------------------------------------------
__global__ void k_gru(const float* __restrict__ resh_in, const float* __restrict__ prev_d,
                      const float* __restrict__ W_ih, const float* __restrict__ b_ih,
                      const float* __restrict__ W_hh, const float* __restrict__ b_hh,
                      float* __restrict__ newd) {
    __shared__ float resh[4][2048];
    __shared__ float pd[4][256];
    const int b0 = blockIdx.x * 4;
    const int tid = threadIdx.x;

    for (int bb = 0; bb < 4; ++bb) {
#pragma unroll
        for (int t = 0; t < 8; ++t)
            resh[bb][t * 256 + tid] = resh_in[(size_t)(b0 + bb) * 2048 + t * 256 + tid];
        pd[bb][tid] = prev_d[(size_t)(b0 + bb) * 256 + tid];
    }
    __syncthreads();

    float ir[4], iz[4], inn[4], hr[4], hz[4], hn[4];
    {
        float bi0 = b_ih[tid], bi1 = b_ih[256 + tid], bi2 = b_ih[512 + tid];
        float bh0 = b_hh[tid], bh1 = b_hh[256 + tid], bh2 = b_hh[512 + tid];
#pragma unroll
        for (int bb = 0; bb < 4; ++bb) {
            ir[bb] = bi0; iz[bb] = bi1; inn[bb] = bi2;
            hr[bb] = bh0; hz[bb] = bh1; hn[bb] = bh2;
        }
    }
    for (int k = 0; k < 2048; ++k) {
        const float* wr = W_ih + (size_t)k * D3;
        float w0 = wr[tid], w1 = wr[256 + tid], w2 = wr[512 + tid];
#pragma unroll
        for (int bb = 0; bb < 4; ++bb) {
            float x = resh[bb][k];
            ir[bb] = fmaf(x, w0, ir[bb]);
            iz[bb] = fmaf(x, w1, iz[bb]);
            inn[bb] = fmaf(x, w2, inn[bb]);
        }
    }
    for (int k = 0; k < 256; ++k) {
        const float* wr = W_hh + (size_t)k * D3;
        float w0 = wr[tid], w1 = wr[256 + tid], w2 = wr[512 + tid];
#pragma unroll
        for (int bb = 0; bb < 4; ++bb) {
            float x = pd[bb][k];
            hr[bb] = fmaf(x, w0, hr[bb]);
            hz[bb] = fmaf(x, w1, hz[bb]);
            hn[bb] = fmaf(x, w2, hn[bb]);
        }
    }
#pragma unroll
    for (int bb = 0; bb < 4; ++bb) {
        float r = 1.f / (1.f + __expf(-(ir[bb] + hr[bb])));
        float z = 1.f / (1.f + __expf(-(iz[bb] + hz[bb])));
        float n = tanhf(inn[bb] + r * hn[bb]);
        newd[(size_t)(b0 + bb) * 256 + tid] = (1.f - z) * n + z * pd[bb][tid];
    }
}

// ---------------------------------------------------------------------------
extern "C" void kernel_launch(void* const* d_in, const int* in_sizes, int n_in,
                              void* d_out, int out_size, void* d_ws, size_t ws_size,
                              hipStream_t stream) {
    const float* prev_d = (const float*)d_in[0];
    const float* x_obs  = (const float*)d_in[1];
    const float* a_prev = (const float*)d_in[2];
    const float* W1     = (const float*)d_in[3];
    const float* b1     = (const float*)d_in[4];
    const float* W2     = (const float*)d_in[5];
    const float* b2     = (const float*)d_in[6];
    const float* Wqkv   = (const float*)d_in[7];
    const float* bqkv   = (const float*)d_in[8];
    const float* Wo     = (const float*)d_in[9];
    const float* bo     = (const float*)d_in[10];
    const float* W_ih   = (const float*)d_in[11];
    const float* b_ih   = (const float*)d_in[12];
    const float* W_hh   = (const float*)d_in[13];
    const float* b_hh   = (const float*)d_in[14];
    float* out = (float*)d_out;

    // ws: xa fp32 (64 MiB) | k bf16 (32 MiB) | v bf16 (32 MiB) | idx (16 KiB)
    const size_t NT = (size_t)BB * SS * DD;
    float* xa = (float*)d_ws;
    __hip_bfloat16* kbf = (__hip_bfloat16*)(xa + NT);
    __hip_bfloat16* vbf = kbf + NT;
    int* idxb = (int*)(vbf + NT);

    float* newd = out;                       // [B, D]
    float* resh = out + (size_t)BB * DD;     // [B, TOPK*D]

    k_xa <<<(BB * SS) / 16, 256, 0, stream>>>(x_obs, a_prev, W1, b1, W2, b2, xa);
    k_kv <<<BB, 256, 0, stream>>>(xa, Wqkv, bqkv, kbf, vbf, idxb);
    k_sel<<<BB, 256, 0, stream>>>(xa, Wqkv, bqkv, kbf, vbf, Wo, bo, idxb, resh);
    k_gru<<<BB / 4, 256, 0, stream>>>(resh, prev_d, W_ih, b_ih, W_hh, b_hh, newd);
}

// Round 5
// 687.683 us; speedup vs baseline: 9.5784x; 1.6258x over previous
//
#include <hip/hip_runtime.h>
#include <hip/hip_bf16.h>
#include <math.h>

#define BB 512
#define SS 128
#define DD 256
#define HH 4
#define TOPK 8
#define D3 768
#define DMA 248
#define ACT_ 8

typedef __attribute__((ext_vector_type(8))) short bf16x8;
typedef __attribute__((ext_vector_type(4))) short short4v;
typedef __attribute__((ext_vector_type(4))) float f32x4;

static __device__ __forceinline__ short f2bf(float x) {
    __hip_bfloat16 h = __float2bfloat16(x);
    return *reinterpret_cast<short*>(&h);
}

// ---------------------------------------------------------------------------
// K1: xa = [ tanh(x_obs@W1+b1)@W2 + b2 , a_prev ]   (16 tokens per block)
// ---------------------------------------------------------------------------
__global__ void k_xa(const float* __restrict__ x_obs, const float* __restrict__ a_prev,
                     const float* __restrict__ W1, const float* __restrict__ b1,
                     const float* __restrict__ W2, const float* __restrict__ b2,
                     float* __restrict__ xa) {
    __shared__ float xsh[16][64];
    __shared__ float hsh[16][256];
    const int t0 = blockIdx.x * 16;
    const int tid = threadIdx.x;

    for (int i = tid; i < 16 * 64; i += 256) {
        int t = i >> 6, c = i & 63;
        xsh[t][c] = x_obs[(size_t)(t0 + t) * 64 + c];
    }
    __syncthreads();

    float acc[16];
    {
        float bias = b1[tid];
#pragma unroll
        for (int t = 0; t < 16; ++t) acc[t] = bias;
        for (int k = 0; k < 64; ++k) {
            float w = W1[k * 256 + tid];
#pragma unroll
            for (int t = 0; t < 16; ++t) acc[t] = fmaf(xsh[t][k], w, acc[t]);
        }
#pragma unroll
        for (int t = 0; t < 16; ++t) hsh[t][tid] = tanhf(acc[t]);
    }
    __syncthreads();

    if (tid < DMA) {
        float bias = b2[tid];
#pragma unroll
        for (int t = 0; t < 16; ++t) acc[t] = bias;
        for (int k = 0; k < 256; ++k) {
            float w = W2[k * DMA + tid];
#pragma unroll
            for (int t = 0; t < 16; ++t) acc[t] = fmaf(hsh[t][k], w, acc[t]);
        }
#pragma unroll
        for (int t = 0; t < 16; ++t) xa[(size_t)(t0 + t) * 256 + tid] = acc[t];
    } else {
        int c = tid - DMA;
#pragma unroll
        for (int t = 0; t < 16; ++t)
            xa[(size_t)(t0 + t) * 256 + tid] = a_prev[(size_t)(t0 + t) * ACT_ + c];
    }
}

// ---------------------------------------------------------------------------
// K_prep: WqT[c][r] = Wq[r][c] (fp32, 256x256); WkvT[n][r] = Wkv[r][n] bf16
//         (512x256). 32x32 LDS tile transpose; 192 blocks.
// ---------------------------------------------------------------------------
__global__ void k_prep(const float* __restrict__ Wqkv, float* __restrict__ WqT,
                       __hip_bfloat16* __restrict__ WkvT) {
    __shared__ float t[32][33];
    const int rt = blockIdx.x / 24, ct = blockIdx.x % 24;
    const int r0 = rt * 32, c0 = ct * 32;
    const int tid = threadIdx.x;
#pragma unroll
    for (int i = 0; i < 4; ++i) {
        int idx = i * 256 + tid;
        int lr = idx >> 5, lc = idx & 31;
        t[lr][lc] = Wqkv[(size_t)(r0 + lr) * D3 + c0 + lc];
    }
    __syncthreads();
#pragma unroll
    for (int i = 0; i < 4; ++i) {
        int idx = i * 256 + tid;
        int lc = idx >> 5, lr = idx & 31;
        float v = t[lr][lc];
        int c = c0 + lc, r = r0 + lr;
        if (c < 256) WqT[(size_t)c * 256 + r] = v;
        else         WkvT[(size_t)(c - 256) * 256 + r] = __float2bfloat16(v);
    }
}

// ---------------------------------------------------------------------------
// K2: per batch: xasum -> ksum -> wqk -> fp64 score rows -> wave top-8.
//     ksum = xasum@Wk + 128*bk  (linearity; no K needed for ordering path)
// ---------------------------------------------------------------------------
__global__ void __launch_bounds__(256) k_score(const float* __restrict__ xa,
        const float* __restrict__ Wqkv, const float* __restrict__ WqT,
        const float* __restrict__ bqkv, int* __restrict__ idxb) {
    __shared__ float xasum_sh[256];
    __shared__ float ksum_sh[256];
    __shared__ float wqk_sh[256];
    __shared__ double ssd[128];
    const int b = blockIdx.x;
    const int tid = threadIdx.x;
    const float* xab = xa + (size_t)b * SS * DD;

    float s = 0.f;
    for (int r = 0; r < 128; ++r) s += xab[r * 256 + tid];
    xasum_sh[tid] = s;
    __syncthreads();

    float ks = 128.f * bqkv[256 + tid];
    for (int d = 0; d < 256; ++d)
        ks = fmaf(xasum_sh[d], Wqkv[(size_t)d * D3 + 256 + tid], ks);
    ksum_sh[tid] = ks;
    __syncthreads();

    float wq = 0.f;
    for (int c = 0; c < 256; ++c)
        wq = fmaf(WqT[(size_t)c * 256 + tid], ksum_sh[c], wq);
    wqk_sh[tid] = wq;
    double bqdot = 0.0;
    for (int c = 0; c < 256; ++c)
        bqdot += (double)bqkv[c] * (double)ksum_sh[c];
    __syncthreads();

    {   // score rows: 2 threads per row, fp64
        int r = tid >> 1, half = tid & 1;
        const float* xr = xab + (size_t)r * 256 + half * 128;
        const float* wk = wqk_sh + half * 128;
        double sd = 0.0;
        for (int d2 = 0; d2 < 128; ++d2) sd += (double)xr[d2] * (double)wk[d2];
        double so = __shfl_xor(sd, 1);
        if (half == 0) ssd[r] = (sd + so + bqdot) * 0.125;
    }
    __syncthreads();
    // wave-parallel top-8, jax semantics (descending, ties -> lower idx)
    if (tid < 64) {
        double v0 = ssd[tid], v1 = ssd[tid + 64];
        int i0 = tid, i1 = tid + 64;
        bool t0 = false, t1 = false;
        for (int t = 0; t < TOPK; ++t) {
            double c0 = t0 ? -1e300 : v0;
            double c1 = t1 ? -1e300 : v1;
            double bvv; int bi;
            if (c1 > c0) { bvv = c1; bi = i1; } else { bvv = c0; bi = i0; }
#pragma unroll
            for (int off = 1; off < 64; off <<= 1) {
                double ov = __shfl_xor(bvv, off);
                int oi = __shfl_xor(bi, off);
                if (ov > bvv || (ov == bvv && oi < bi)) { bvv = ov; bi = oi; }
            }
            if (tid == 0) idxb[b * TOPK + t] = bi;
            if (bi == i0) t0 = true;
            if (bi == i1) t1 = true;
        }
    }
}

// ---------------------------------------------------------------------------
// K3: bf16 MFMA K/V GEMM: per (b, ntile): [128 tok x 256] @ [256 x 128 cols]
//     of Wkv (+bias), output bf16 K/V. 4 waves, 64x64 per wave, BK=32.
// ---------------------------------------------------------------------------
__global__ void __launch_bounds__(256) k_kvmm(const float* __restrict__ xa,
        const __hip_bfloat16* __restrict__ WkvT, const float* __restrict__ bqkv,
        __hip_bfloat16* __restrict__ kbf, __hip_bfloat16* __restrict__ vbf) {
    __shared__ short Ash[128 * 36];   // bf16 A tile [token][k], stride 36
    __shared__ short Bsh[128 * 36];   // bf16 B tile [n][k], stride 36
    const int b = blockIdx.x >> 2, ntile = blockIdx.x & 3;
    const int tid = threadIdx.x;
    const int wave = tid >> 6, lane = tid & 63;
    const int wm = wave >> 1, wn = wave & 1;
    const int quad = lane >> 4, l15 = lane & 15;
    const float* xab = xa + (size_t)b * SS * DD;

    f32x4 acc[4][4];
#pragma unroll
    for (int tn = 0; tn < 4; ++tn) {
        int n_g = ntile * 128 + wn * 64 + tn * 16 + l15;
        float bias = bqkv[256 + n_g];
#pragma unroll
        for (int tm = 0; tm < 4; ++tm)
            acc[tm][tn] = (f32x4){bias, bias, bias, bias};
    }

    for (int k0 = 0; k0 < 256; k0 += 32) {
        __syncthreads();
        // stage A: 128 rows x 32 k (fp32 -> bf16)
#pragma unroll
        for (int it = 0; it < 4; ++it) {
            int idx = it * 256 + tid;
            int row = idx >> 3, f4 = idx & 7;
            float4 x4 = *(const float4*)&xab[(size_t)row * 256 + k0 + f4 * 4];
            short4v sv = { f2bf(x4.x), f2bf(x4.y), f2bf(x4.z), f2bf(x4.w) };
            *(short4v*)&Ash[row * 36 + f4 * 4] = sv;
        }
        // stage B: 128 n-rows x 32 k (already bf16, transposed layout)
#pragma unroll
        for (int it = 0; it < 2; ++it) {
            int idx = it * 256 + tid;
            int nr = idx >> 2, q4 = idx & 3;
            uint4 w = *(const uint4*)&WkvT[((size_t)(ntile * 128 + nr)) * 256 + k0 + q4 * 8];
            *(short4v*)&Bsh[nr * 36 + q4 * 8]     = ((short4v*)&w)[0];
            *(short4v*)&Bsh[nr * 36 + q4 * 8 + 4] = ((short4v*)&w)[1];
        }
        __syncthreads();

        bf16x8 af[4], bfr[4];
#pragma unroll
        for (int t = 0; t < 4; ++t) {
            int ar = (wm * 64 + t * 16 + l15) * 36 + quad * 8;
            short4v lo = *(short4v*)&Ash[ar];
            short4v hi = *(short4v*)&Ash[ar + 4];
            bf16x8 f;
            f[0]=lo[0]; f[1]=lo[1]; f[2]=lo[2]; f[3]=lo[3];
            f[4]=hi[0]; f[5]=hi[1]; f[6]=hi[2]; f[7]=hi[3];
            af[t] = f;
            int br = (wn * 64 + t * 16 + l15) * 36 + quad * 8;
            short4v blo = *(short4v*)&Bsh[br];
            short4v bhi = *(short4v*)&Bsh[br + 4];
            bf16x8 g;
            g[0]=blo[0]; g[1]=blo[1]; g[2]=blo[2]; g[3]=blo[3];
            g[4]=bhi[0]; g[5]=bhi[1]; g[6]=bhi[2]; g[7]=bhi[3];
            bfr[t] = g;
        }
#pragma unroll
        for (int tm = 0; tm < 4; ++tm)
#pragma unroll
            for (int tn = 0; tn < 4; ++tn)
                acc[tm][tn] = __builtin_amdgcn_mfma_f32_16x16x32_bf16(
                    af[tm], bfr[tn], acc[tm][tn], 0, 0, 0);
    }
    // epilogue: D col = l15, row = quad*4 + r
#pragma unroll
    for (int tn = 0; tn < 4; ++tn) {
        int n_g = ntile * 128 + wn * 64 + tn * 16 + l15;
        __hip_bfloat16* dst = (n_g < 256) ? kbf : vbf;
        int nc = n_g & 255;
#pragma unroll
        for (int tm = 0; tm < 4; ++tm) {
#pragma unroll
            for (int r = 0; r < 4; ++r) {
                int token = wm * 64 + tm * 16 + quad * 4 + r;
                dst[((size_t)b * SS + token) * 256 + nc] = __float2bfloat16(acc[tm][tn][r]);
            }
        }
    }
}

// ---------------------------------------------------------------------------
// K4: per b: recompute q for the 8 selected rows, per-head softmax(q·k)·v,
//     Wo + bo -> reshaped rows into d_out.
// ---------------------------------------------------------------------------
__global__ void __launch_bounds__(256) k_sel(const float* __restrict__ xa,
        const float* __restrict__ Wqkv, const float* __restrict__ bqkv,
        const __hip_bfloat16* __restrict__ kbf, const __hip_bfloat16* __restrict__ vbf,
        const float* __restrict__ Wo, const float* __restrict__ bo,
        const int* __restrict__ idxb, float* __restrict__ resh_out) {
    __shared__ float xsel[8][256];
    __shared__ float qsel[8][256];
    __shared__ __hip_bfloat16 ksh[128][66];
    __shared__ __hip_bfloat16 vsh[128][66];
    __shared__ float sbuf[8][128];
    __shared__ float ctxh[8][64];
    __shared__ int sidx[8];
    const int b = blockIdx.x;
    const int tid = threadIdx.x;
    const float* xab = xa + (size_t)b * SS * DD;

    if (tid < 8) sidx[tid] = idxb[b * TOPK + tid];
    __syncthreads();
#pragma unroll
    for (int t = 0; t < 8; ++t) xsel[t][tid] = xab[(size_t)sidx[t] * 256 + tid];
    __syncthreads();
    {
        float a[8];
        float bq = bqkv[tid];
#pragma unroll
        for (int t = 0; t < 8; ++t) a[t] = bq;
        for (int kk = 0; kk < 256; ++kk) {
            float w = Wqkv[(size_t)kk * D3 + tid];
#pragma unroll
            for (int t = 0; t < 8; ++t) a[t] = fmaf(xsel[t][kk], w, a[t]);
        }
#pragma unroll
        for (int t = 0; t < 8; ++t) qsel[t][tid] = a[t];
    }
    float racc[8];
#pragma unroll
    for (int r = 0; r < 8; ++r) racc[r] = 0.f;

    for (int h = 0; h < 4; ++h) {
        __syncthreads();
        for (int it = 0; it < 32; ++it) {
            int id = it * 256 + tid;
            int row = id >> 6, col = id & 63;
            size_t g = ((size_t)b * SS + row) * 256 + h * 64 + col;
            ksh[row][col] = kbf[g];
            vsh[row][col] = vbf[g];
        }
        __syncthreads();
#pragma unroll
        for (int j = 0; j < 4; ++j) {
            int id = j * 256 + tid;
            int row = id >> 7, col = id & 127;
            float s = 0.f;
            for (int d = 0; d < 64; ++d)
                s = fmaf(qsel[row][h * 64 + d], __bfloat162float(ksh[col][d]), s);
            sbuf[row][col] = s * 0.125f;
        }
        __syncthreads();
        if (tid < 8) {
            float m = -3.4e38f;
            for (int k2 = 0; k2 < 128; ++k2) m = fmaxf(m, sbuf[tid][k2]);
            float ssum = 0.f;
            for (int k2 = 0; k2 < 128; ++k2) {
                float e = __expf(sbuf[tid][k2] - m);
                sbuf[tid][k2] = e;
                ssum += e;
            }
            float inv = 1.f / ssum;
            for (int k2 = 0; k2 < 128; ++k2) sbuf[tid][k2] *= inv;
        }
        __syncthreads();
#pragma unroll
        for (int j = 0; j < 2; ++j) {
            int id = j * 256 + tid;
            int row = id >> 6, col = id & 63;
            float c = 0.f;
            for (int k2 = 0; k2 < 128; ++k2)
                c = fmaf(sbuf[row][k2], __bfloat162float(vsh[k2][col]), c);
            ctxh[row][col] = c;
        }
        __syncthreads();
        for (int jj = 0; jj < 64; ++jj) {
            float w = Wo[(size_t)(h * 64 + jj) * 256 + tid];
#pragma unroll
            for (int r = 0; r < 8; ++r) racc[r] = fmaf(ctxh[r][jj], w, racc[r]);
        }
    }
    float bov = bo[tid];
#pragma unroll
    for (int r = 0; r < 8; ++r)
        resh_out[(size_t)b * 2048 + r * 256 + tid] = racc[r] + bov;
}

// ---------------------------------------------------------------------------
// K5: GRUCell. 4 batch rows per block.
// ---------------------------------------------------------------------------
__global__ void k_gru(const float* __restrict__ resh_in, const float* __restrict__ prev_d,
                      const float* __restrict__ W_ih, const float* __restrict__ b_ih,
                      const float* __restrict__ W_hh, const float* __restrict__ b_hh,
                      float* __restrict__ newd) {
    __shared__ float resh[4][2048];
    __shared__ float pd[4][256];
    const int b0 = blockIdx.x * 4;
    const int tid = threadIdx.x;

    for (int bb = 0; bb < 4; ++bb) {
#pragma unroll
        for (int t = 0; t < 8; ++t)
            resh[bb][t * 256 + tid] = resh_in[(size_t)(b0 + bb) * 2048 + t * 256 + tid];
        pd[bb][tid] = prev_d[(size_t)(b0 + bb) * 256 + tid];
    }
    __syncthreads();

    float ir[4], iz[4], inn[4], hr[4], hz[4], hn[4];
    {
        float bi0 = b_ih[tid], bi1 = b_ih[256 + tid], bi2 = b_ih[512 + tid];
        float bh0 = b_hh[tid], bh1 = b_hh[256 + tid], bh2 = b_hh[512 + tid];
#pragma unroll
        for (int bb = 0; bb < 4; ++bb) {
            ir[bb] = bi0; iz[bb] = bi1; inn[bb] = bi2;
            hr[bb] = bh0; hz[bb] = bh1; hn[bb] = bh2;
        }
    }
    for (int k = 0; k < 2048; ++k) {
        const float* wr = W_ih + (size_t)k * D3;
        float w0 = wr[tid], w1 = wr[256 + tid], w2 = wr[512 + tid];
#pragma unroll
        for (int bb = 0; bb < 4; ++bb) {
            float x = resh[bb][k];
            ir[bb] = fmaf(x, w0, ir[bb]);
            iz[bb] = fmaf(x, w1, iz[bb]);
            inn[bb] = fmaf(x, w2, inn[bb]);
        }
    }
    for (int k = 0; k < 256; ++k) {
        const float* wr = W_hh + (size_t)k * D3;
        float w0 = wr[tid], w1 = wr[256 + tid], w2 = wr[512 + tid];
#pragma unroll
        for (int bb = 0; bb < 4; ++bb) {
            float x = pd[bb][k];
            hr[bb] = fmaf(x, w0, hr[bb]);
            hz[bb] = fmaf(x, w1, hz[bb]);
            hn[bb] = fmaf(x, w2, hn[bb]);
        }
    }
#pragma unroll
    for (int bb = 0; bb < 4; ++bb) {
        float r = 1.f / (1.f + __expf(-(ir[bb] + hr[bb])));
        float z = 1.f / (1.f + __expf(-(iz[bb] + hz[bb])));
        float n = tanhf(inn[bb] + r * hn[bb]);
        newd[(size_t)(b0 + bb) * 256 + tid] = (1.f - z) * n + z * pd[bb][tid];
    }
}

// ---------------------------------------------------------------------------
extern "C" void kernel_launch(void* const* d_in, const int* in_sizes, int n_in,
                              void* d_out, int out_size, void* d_ws, size_t ws_size,
                              hipStream_t stream) {
    const float* prev_d = (const float*)d_in[0];
    const float* x_obs  = (const float*)d_in[1];
    const float* a_prev = (const float*)d_in[2];
    const float* W1     = (const float*)d_in[3];
    const float* b1     = (const float*)d_in[4];
    const float* W2     = (const float*)d_in[5];
    const float* b2     = (const float*)d_in[6];
    const float* Wqkv   = (const float*)d_in[7];
    const float* bqkv   = (const float*)d_in[8];
    const float* Wo     = (const float*)d_in[9];
    const float* bo     = (const float*)d_in[10];
    const float* W_ih   = (const float*)d_in[11];
    const float* b_ih   = (const float*)d_in[12];
    const float* W_hh   = (const float*)d_in[13];
    const float* b_hh   = (const float*)d_in[14];
    float* out = (float*)d_out;

    // ws: xa fp32 64MB | kbf 32MB | vbf 32MB | WqT 256KB | WkvT 256KB | idx
    const size_t NT = (size_t)BB * SS * DD;
    float* xa = (float*)d_ws;
    __hip_bfloat16* kbf = (__hip_bfloat16*)(xa + NT);
    __hip_bfloat16* vbf = kbf + NT;
    float* WqT = (float*)(vbf + NT);
    __hip_bfloat16* WkvT = (__hip_bfloat16*)(WqT + 256 * 256);
    int* idxb = (int*)(WkvT + 512 * 256);

    float* newd = out;                       // [B, D]
    float* resh = out + (size_t)BB * DD;     // [B, TOPK*D]

    k_xa   <<<(BB * SS) / 16, 256, 0, stream>>>(x_obs, a_prev, W1, b1, W2, b2, xa);
    k_prep <<<192, 256, 0, stream>>>(Wqkv, WqT, WkvT);
    k_score<<<BB, 256, 0, stream>>>(xa, Wqkv, WqT, bqkv, idxb);
    k_kvmm <<<BB * 4, 256, 0, stream>>>(xa, WkvT, bqkv, kbf, vbf);
    k_sel  <<<BB, 256, 0, stream>>>(xa, Wqkv, bqkv, kbf, vbf, Wo, bo, idxb, resh);
    k_gru  <<<BB / 4, 256, 0, stream>>>(resh, prev_d, W_ih, b_ih, W_hh, b_hh, newd);
}

// Round 6
// 543.633 us; speedup vs baseline: 12.1165x; 1.2650x over previous
//
#include <hip/hip_runtime.h>
#include <hip/hip_bf16.h>
#include <math.h>

#define BB 512
#define SS 128
#define DD 256
#define HH 4
#define TOPK 8
#define D3 768
#define DMA 248
#define ACT_ 8

typedef __attribute__((ext_vector_type(8))) short bf16x8;
typedef __attribute__((ext_vector_type(4))) short short4v;
typedef __attribute__((ext_vector_type(4))) float f32x4;

static __device__ __forceinline__ short f2bf(float x) {
    __hip_bfloat16 h = __float2bfloat16(x);
    return *reinterpret_cast<short*>(&h);
}

// ---------------------------------------------------------------------------
// K1: xa = [ tanh(x_obs@W1+b1)@W2 + b2 , a_prev ]   (16 tokens per block)
// ---------------------------------------------------------------------------
__global__ void k_xa(const float* __restrict__ x_obs, const float* __restrict__ a_prev,
                     const float* __restrict__ W1, const float* __restrict__ b1,
                     const float* __restrict__ W2, const float* __restrict__ b2,
                     float* __restrict__ xa) {
    __shared__ float xsh[16][64];
    __shared__ float hsh[16][256];
    const int t0 = blockIdx.x * 16;
    const int tid = threadIdx.x;

    for (int i = tid; i < 16 * 64; i += 256) {
        int t = i >> 6, c = i & 63;
        xsh[t][c] = x_obs[(size_t)(t0 + t) * 64 + c];
    }
    __syncthreads();

    float acc[16];
    {
        float bias = b1[tid];
#pragma unroll
        for (int t = 0; t < 16; ++t) acc[t] = bias;
        for (int k = 0; k < 64; ++k) {
            float w = W1[k * 256 + tid];
#pragma unroll
            for (int t = 0; t < 16; ++t) acc[t] = fmaf(xsh[t][k], w, acc[t]);
        }
#pragma unroll
        for (int t = 0; t < 16; ++t) hsh[t][tid] = tanhf(acc[t]);
    }
    __syncthreads();

    if (tid < DMA) {
        float bias = b2[tid];
#pragma unroll
        for (int t = 0; t < 16; ++t) acc[t] = bias;
        for (int k = 0; k < 256; ++k) {
            float w = W2[k * DMA + tid];
#pragma unroll
            for (int t = 0; t < 16; ++t) acc[t] = fmaf(hsh[t][k], w, acc[t]);
        }
#pragma unroll
        for (int t = 0; t < 16; ++t) xa[(size_t)(t0 + t) * 256 + tid] = acc[t];
    } else {
        int c = tid - DMA;
#pragma unroll
        for (int t = 0; t < 16; ++t)
            xa[(size_t)(t0 + t) * 256 + tid] = a_prev[(size_t)(t0 + t) * ACT_ + c];
    }
}

// ---------------------------------------------------------------------------
// K_prep: WqT fp32 [256x256] transpose; WkvT bf16 [512x256]. 192 blocks.
// ---------------------------------------------------------------------------
__global__ void k_prep(const float* __restrict__ Wqkv, float* __restrict__ WqT,
                       __hip_bfloat16* __restrict__ WkvT) {
    __shared__ float t[32][33];
    const int rt = blockIdx.x / 24, ct = blockIdx.x % 24;
    const int r0 = rt * 32, c0 = ct * 32;
    const int tid = threadIdx.x;
#pragma unroll
    for (int i = 0; i < 4; ++i) {
        int idx = i * 256 + tid;
        int lr = idx >> 5, lc = idx & 31;
        t[lr][lc] = Wqkv[(size_t)(r0 + lr) * D3 + c0 + lc];
    }
    __syncthreads();
#pragma unroll
    for (int i = 0; i < 4; ++i) {
        int idx = i * 256 + tid;
        int lc = idx >> 5, lr = idx & 31;
        float v = t[lr][lc];
        int c = c0 + lc, r = r0 + lr;
        if (c < 256) WqT[(size_t)c * 256 + r] = v;
        else         WkvT[(size_t)(c - 256) * 256 + r] = __float2bfloat16(v);
    }
}

// ---------------------------------------------------------------------------
// K_trbf: generic fp32 [R x C] -> bf16 transposed [C x R]. 32x32 tiles.
// ---------------------------------------------------------------------------
__global__ void k_trbf(const float* __restrict__ src, __hip_bfloat16* __restrict__ dst,
                       int R, int C) {
    __shared__ float t[32][33];
    const int ctiles = C >> 5;
    const int rt = blockIdx.x / ctiles, ct = blockIdx.x % ctiles;
    const int r0 = rt * 32, c0 = ct * 32;
    const int tid = threadIdx.x;
#pragma unroll
    for (int i = 0; i < 4; ++i) {
        int idx = i * 256 + tid;
        int lr = idx >> 5, lc = idx & 31;
        t[lr][lc] = src[(size_t)(r0 + lr) * C + c0 + lc];
    }
    __syncthreads();
#pragma unroll
    for (int i = 0; i < 4; ++i) {
        int idx = i * 256 + tid;
        int lc = idx >> 5, lr = idx & 31;
        dst[(size_t)(c0 + lc) * R + r0 + lr] = __float2bfloat16(t[lr][lc]);
    }
}

// ---------------------------------------------------------------------------
// K_pdcast: prev_d fp32 -> bf16
// ---------------------------------------------------------------------------
__global__ void k_pdcast(const float* __restrict__ src, __hip_bfloat16* __restrict__ dst) {
    int i = blockIdx.x * 1024 + threadIdx.x * 4;
    float4 v = *(const float4*)&src[i];
    dst[i]     = __float2bfloat16(v.x);
    dst[i + 1] = __float2bfloat16(v.y);
    dst[i + 2] = __float2bfloat16(v.z);
    dst[i + 3] = __float2bfloat16(v.w);
}

// ---------------------------------------------------------------------------
// K2: per batch: xasum -> ksum -> wqk -> fp64 score rows -> wave top-8.
// ---------------------------------------------------------------------------
__global__ void __launch_bounds__(256) k_score(const float* __restrict__ xa,
        const float* __restrict__ Wqkv, const float* __restrict__ WqT,
        const float* __restrict__ bqkv, int* __restrict__ idxb) {
    __shared__ float xasum_sh[256];
    __shared__ float ksum_sh[256];
    __shared__ float wqk_sh[256];
    __shared__ double ssd[128];
    const int b = blockIdx.x;
    const int tid = threadIdx.x;
    const float* xab = xa + (size_t)b * SS * DD;

    float s = 0.f;
    for (int r = 0; r < 128; ++r) s += xab[r * 256 + tid];
    xasum_sh[tid] = s;
    __syncthreads();

    float ks = 128.f * bqkv[256 + tid];
    for (int d = 0; d < 256; ++d)
        ks = fmaf(xasum_sh[d], Wqkv[(size_t)d * D3 + 256 + tid], ks);
    ksum_sh[tid] = ks;
    __syncthreads();

    float wq = 0.f;
    for (int c = 0; c < 256; ++c)
        wq = fmaf(WqT[(size_t)c * 256 + tid], ksum_sh[c], wq);
    wqk_sh[tid] = wq;
    double bqdot = 0.0;
    for (int c = 0; c < 256; ++c)
        bqdot += (double)bqkv[c] * (double)ksum_sh[c];
    __syncthreads();

    {
        int r = tid >> 1, half = tid & 1;
        const float* xr = xab + (size_t)r * 256 + half * 128;
        const float* wk = wqk_sh + half * 128;
        double sd = 0.0;
        for (int d2 = 0; d2 < 128; ++d2) sd += (double)xr[d2] * (double)wk[d2];
        double so = __shfl_xor(sd, 1);
        if (half == 0) ssd[r] = (sd + so + bqdot) * 0.125;
    }
    __syncthreads();
    if (tid < 64) {
        double v0 = ssd[tid], v1 = ssd[tid + 64];
        int i0 = tid, i1 = tid + 64;
        bool t0 = false, t1 = false;
        for (int t = 0; t < TOPK; ++t) {
            double c0 = t0 ? -1e300 : v0;
            double c1 = t1 ? -1e300 : v1;
            double bvv; int bi;
            if (c1 > c0) { bvv = c1; bi = i1; } else { bvv = c0; bi = i0; }
#pragma unroll
            for (int off = 1; off < 64; off <<= 1) {
                double ov = __shfl_xor(bvv, off);
                int oi = __shfl_xor(bi, off);
                if (ov > bvv || (ov == bvv && oi < bi)) { bvv = ov; bi = oi; }
            }
            if (tid == 0) idxb[b * TOPK + t] = bi;
            if (bi == i0) t0 = true;
            if (bi == i1) t1 = true;
        }
    }
}

// ---------------------------------------------------------------------------
// K3: bf16 MFMA K/V GEMM (test-verified fragment pattern)
// ---------------------------------------------------------------------------
__global__ void __launch_bounds__(256) k_kvmm(const float* __restrict__ xa,
        const __hip_bfloat16* __restrict__ WkvT, const float* __restrict__ bqkv,
        __hip_bfloat16* __restrict__ kbf, __hip_bfloat16* __restrict__ vbf) {
    __shared__ short Ash[128 * 36];
    __shared__ short Bsh[128 * 36];
    const int b = blockIdx.x >> 2, ntile = blockIdx.x & 3;
    const int tid = threadIdx.x;
    const int wave = tid >> 6, lane = tid & 63;
    const int wm = wave >> 1, wn = wave & 1;
    const int quad = lane >> 4, l15 = lane & 15;
    const float* xab = xa + (size_t)b * SS * DD;

    f32x4 acc[4][4];
#pragma unroll
    for (int tn = 0; tn < 4; ++tn) {
        int n_g = ntile * 128 + wn * 64 + tn * 16 + l15;
        float bias = bqkv[256 + n_g];
#pragma unroll
        for (int tm = 0; tm < 4; ++tm)
            acc[tm][tn] = (f32x4){bias, bias, bias, bias};
    }

    for (int k0 = 0; k0 < 256; k0 += 32) {
        __syncthreads();
#pragma unroll
        for (int it = 0; it < 4; ++it) {
            int idx = it * 256 + tid;
            int row = idx >> 3, f4 = idx & 7;
            float4 x4 = *(const float4*)&xab[(size_t)row * 256 + k0 + f4 * 4];
            short4v sv = { f2bf(x4.x), f2bf(x4.y), f2bf(x4.z), f2bf(x4.w) };
            *(short4v*)&Ash[row * 36 + f4 * 4] = sv;
        }
#pragma unroll
        for (int it = 0; it < 2; ++it) {
            int idx = it * 256 + tid;
            int nr = idx >> 2, q4 = idx & 3;
            uint4 w = *(const uint4*)&WkvT[((size_t)(ntile * 128 + nr)) * 256 + k0 + q4 * 8];
            *(short4v*)&Bsh[nr * 36 + q4 * 8]     = ((short4v*)&w)[0];
            *(short4v*)&Bsh[nr * 36 + q4 * 8 + 4] = ((short4v*)&w)[1];
        }
        __syncthreads();

        bf16x8 af[4], bfr[4];
#pragma unroll
        for (int t = 0; t < 4; ++t) {
            int ar = (wm * 64 + t * 16 + l15) * 36 + quad * 8;
            short4v lo = *(short4v*)&Ash[ar];
            short4v hi = *(short4v*)&Ash[ar + 4];
            bf16x8 f;
            f[0]=lo[0]; f[1]=lo[1]; f[2]=lo[2]; f[3]=lo[3];
            f[4]=hi[0]; f[5]=hi[1]; f[6]=hi[2]; f[7]=hi[3];
            af[t] = f;
            int br = (wn * 64 + t * 16 + l15) * 36 + quad * 8;
            short4v blo = *(short4v*)&Bsh[br];
            short4v bhi = *(short4v*)&Bsh[br + 4];
            bf16x8 g;
            g[0]=blo[0]; g[1]=blo[1]; g[2]=blo[2]; g[3]=blo[3];
            g[4]=bhi[0]; g[5]=bhi[1]; g[6]=bhi[2]; g[7]=bhi[3];
            bfr[t] = g;
        }
#pragma unroll
        for (int tm = 0; tm < 4; ++tm)
#pragma unroll
            for (int tn = 0; tn < 4; ++tn)
                acc[tm][tn] = __builtin_amdgcn_mfma_f32_16x16x32_bf16(
                    af[tm], bfr[tn], acc[tm][tn], 0, 0, 0);
    }
#pragma unroll
    for (int tn = 0; tn < 4; ++tn) {
        int n_g = ntile * 128 + wn * 64 + tn * 16 + l15;
        __hip_bfloat16* dst = (n_g < 256) ? kbf : vbf;
        int nc = n_g & 255;
#pragma unroll
        for (int tm = 0; tm < 4; ++tm) {
#pragma unroll
            for (int r = 0; r < 4; ++r) {
                int token = wm * 64 + tm * 16 + quad * 4 + r;
                dst[((size_t)b * SS + token) * 256 + nc] = __float2bfloat16(acc[tm][tn][r]);
            }
        }
    }
}

// ---------------------------------------------------------------------------
// K_gemm_bf: C[M x N] fp32 = A_bf[M x K] @ BT_bf[N x K]^T. 128x128 tile, BK=64.
// ---------------------------------------------------------------------------
__global__ void __launch_bounds__(256) k_gemm_bf(const __hip_bfloat16* __restrict__ A,
        const __hip_bfloat16* __restrict__ BT, float* __restrict__ C,
        int K, int N, int ntiles) {
    __shared__ __attribute__((aligned(16))) short Ash[128 * 72];
    __shared__ __attribute__((aligned(16))) short Bsh[128 * 72];
    const int mt = blockIdx.x / ntiles, nt = blockIdx.x % ntiles;
    const int m0 = mt * 128, n0 = nt * 128;
    const int tid = threadIdx.x;
    const int wave = tid >> 6, lane = tid & 63;
    const int wm = wave >> 1, wn = wave & 1;
    const int quad = lane >> 4, l15 = lane & 15;

    f32x4 acc[4][4];
#pragma unroll
    for (int tm = 0; tm < 4; ++tm)
#pragma unroll
        for (int tn = 0; tn < 4; ++tn)
            acc[tm][tn] = (f32x4){0.f, 0.f, 0.f, 0.f};

    for (int k0 = 0; k0 < K; k0 += 64) {
        __syncthreads();
#pragma unroll
        for (int it = 0; it < 4; ++it) {
            int idx = it * 256 + tid;
            int row = idx >> 3, c8 = idx & 7;
            *(uint4*)&Ash[row * 72 + c8 * 8] =
                *(const uint4*)&A[(size_t)(m0 + row) * K + k0 + c8 * 8];
            *(uint4*)&Bsh[row * 72 + c8 * 8] =
                *(const uint4*)&BT[(size_t)(n0 + row) * K + k0 + c8 * 8];
        }
        __syncthreads();
#pragma unroll
        for (int ks = 0; ks < 2; ++ks) {
            bf16x8 af[4], bfr[4];
#pragma unroll
            for (int t = 0; t < 4; ++t) {
                af[t]  = *(bf16x8*)&Ash[(wm * 64 + t * 16 + l15) * 72 + ks * 32 + quad * 8];
                bfr[t] = *(bf16x8*)&Bsh[(wn * 64 + t * 16 + l15) * 72 + ks * 32 + quad * 8];
            }
#pragma unroll
            for (int tm = 0; tm < 4; ++tm)
#pragma unroll
                for (int tn = 0; tn < 4; ++tn)
                    acc[tm][tn] = __builtin_amdgcn_mfma_f32_16x16x32_bf16(
                        af[tm], bfr[tn], acc[tm][tn], 0, 0, 0);
        }
    }
#pragma unroll
    for (int tm = 0; tm < 4; ++tm)
#pragma unroll
        for (int tn = 0; tn < 4; ++tn) {
            int col = n0 + wn * 64 + tn * 16 + l15;
#pragma unroll
            for (int r = 0; r < 4; ++r) {
                int row = m0 + wm * 64 + tm * 16 + quad * 4 + r;
                C[(size_t)row * N + col] = acc[tm][tn][r];
            }
        }
}

// ---------------------------------------------------------------------------
// K_gruact: gates elementwise. newd = (1-z)*n + z*prev_d
// ---------------------------------------------------------------------------
__global__ void k_gruact(const float* __restrict__ gi, const float* __restrict__ gh,
                         const float* __restrict__ b_ih, const float* __restrict__ b_hh,
                         const float* __restrict__ prev_d, float* __restrict__ newd) {
    const int b = blockIdx.x, tid = threadIdx.x;
    const float* gib = gi + (size_t)b * D3;
    const float* ghb = gh + (size_t)b * D3;
    float ir = gib[tid] + b_ih[tid];
    float iz = gib[256 + tid] + b_ih[256 + tid];
    float in = gib[512 + tid] + b_ih[512 + tid];
    float hr = ghb[tid] + b_hh[tid];
    float hz = ghb[256 + tid] + b_hh[256 + tid];
    float hn = ghb[512 + tid] + b_hh[512 + tid];
    float pd = prev_d[(size_t)b * 256 + tid];
    float r = 1.f / (1.f + __expf(-(ir + hr)));
    float z = 1.f / (1.f + __expf(-(iz + hz)));
    float n = tanhf(in + r * hn);
    newd[(size_t)b * 256 + tid] = (1.f - z) * n + z * pd;
}

// ---------------------------------------------------------------------------
// K4: per b: recompute q for the 8 selected rows, per-head softmax(q·k)·v,
//     Wo + bo -> reshaped rows into d_out (fp32) + resh_bf (bf16) for GRU.
// ---------------------------------------------------------------------------
__global__ void __launch_bounds__(256) k_sel(const float* __restrict__ xa,
        const float* __restrict__ Wqkv, const float* __restrict__ bqkv,
        const __hip_bfloat16* __restrict__ kbf, const __hip_bfloat16* __restrict__ vbf,
        const float* __restrict__ Wo, const float* __restrict__ bo,
        const int* __restrict__ idxb, float* __restrict__ resh_out,
        __hip_bfloat16* __restrict__ resh_bf) {
    __shared__ float xsel[8][256];
    __shared__ float qsel[8][256];
    __shared__ __hip_bfloat16 ksh[128][66];
    __shared__ __hip_bfloat16 vsh[128][66];
    __shared__ float sbuf[8][128];
    __shared__ float ctxh[8][64];
    __shared__ int sidx[8];
    const int b = blockIdx.x;
    const int tid = threadIdx.x;
    const float* xab = xa + (size_t)b * SS * DD;

    if (tid < 8) sidx[tid] = idxb[b * TOPK + tid];
    __syncthreads();
#pragma unroll
    for (int t = 0; t < 8; ++t) xsel[t][tid] = xab[(size_t)sidx[t] * 256 + tid];
    __syncthreads();
    {
        float a[8];
        float bq = bqkv[tid];
#pragma unroll
        for (int t = 0; t < 8; ++t) a[t] = bq;
        for (int kk = 0; kk < 256; ++kk) {
            float w = Wqkv[(size_t)kk * D3 + tid];
#pragma unroll
            for (int t = 0; t < 8; ++t) a[t] = fmaf(xsel[t][kk], w, a[t]);
        }
#pragma unroll
        for (int t = 0; t < 8; ++t) qsel[t][tid] = a[t];
    }
    float racc[8];
#pragma unroll
    for (int r = 0; r < 8; ++r) racc[r] = 0.f;

    for (int h = 0; h < 4; ++h) {
        __syncthreads();
        for (int it = 0; it < 32; ++it) {
            int id = it * 256 + tid;
            int row = id >> 6, col = id & 63;
            size_t g = ((size_t)b * SS + row) * 256 + h * 64 + col;
            ksh[row][col] = kbf[g];
            vsh[row][col] = vbf[g];
        }
        __syncthreads();
#pragma unroll
        for (int j = 0; j < 4; ++j) {
            int id = j * 256 + tid;
            int row = id >> 7, col = id & 127;
            float s = 0.f;
            for (int d = 0; d < 64; ++d)
                s = fmaf(qsel[row][h * 64 + d], __bfloat162float(ksh[col][d]), s);
            sbuf[row][col] = s * 0.125f;
        }
        __syncthreads();
        if (tid < 8) {
            float m = -3.4e38f;
            for (int k2 = 0; k2 < 128; ++k2) m = fmaxf(m, sbuf[tid][k2]);
            float ssum = 0.f;
            for (int k2 = 0; k2 < 128; ++k2) {
                float e = __expf(sbuf[tid][k2] - m);
                sbuf[tid][k2] = e;
                ssum += e;
            }
            float inv = 1.f / ssum;
            for (int k2 = 0; k2 < 128; ++k2) sbuf[tid][k2] *= inv;
        }
        __syncthreads();
#pragma unroll
        for (int j = 0; j < 2; ++j) {
            int id = j * 256 + tid;
            int row = id >> 6, col = id & 63;
            float c = 0.f;
            for (int k2 = 0; k2 < 128; ++k2)
                c = fmaf(sbuf[row][k2], __bfloat162float(vsh[k2][col]), c);
            ctxh[row][col] = c;
        }
        __syncthreads();
        for (int jj = 0; jj < 64; ++jj) {
            float w = Wo[(size_t)(h * 64 + jj) * 256 + tid];
#pragma unroll
            for (int r = 0; r < 8; ++r) racc[r] = fmaf(ctxh[r][jj], w, racc[r]);
        }
    }
    float bov = bo[tid];
#pragma unroll
    for (int r = 0; r < 8; ++r) {
        float v = racc[r] + bov;
        resh_out[(size_t)b * 2048 + r * 256 + tid] = v;
        resh_bf[(size_t)b * 2048 + r * 256 + tid] = __float2bfloat16(v);
    }
}

// ---------------------------------------------------------------------------
extern "C" void kernel_launch(void* const* d_in, const int* in_sizes, int n_in,
                              void* d_out, int out_size, void* d_ws, size_t ws_size,
                              hipStream_t stream) {
    const float* prev_d = (const float*)d_in[0];
    const float* x_obs  = (const float*)d_in[1];
    const float* a_prev = (const float*)d_in[2];
    const float* W1     = (const float*)d_in[3];
    const float* b1     = (const float*)d_in[4];
    const float* W2     = (const float*)d_in[5];
    const float* b2     = (const float*)d_in[6];
    const float* Wqkv   = (const float*)d_in[7];
    const float* bqkv   = (const float*)d_in[8];
    const float* Wo     = (const float*)d_in[9];
    const float* bo     = (const float*)d_in[10];
    const float* W_ih   = (const float*)d_in[11];
    const float* b_ih   = (const float*)d_in[12];
    const float* W_hh   = (const float*)d_in[13];
    const float* b_hh   = (const float*)d_in[14];
    float* out = (float*)d_out;

    const size_t NT = (size_t)BB * SS * DD;
    float* xa = (float*)d_ws;                                   // 67 MB
    __hip_bfloat16* kbf = (__hip_bfloat16*)(xa + NT);           // 33.5 MB
    __hip_bfloat16* vbf = kbf + NT;                             // 33.5 MB
    float* WqT = (float*)(vbf + NT);                            // 256 KB
    __hip_bfloat16* WkvT = (__hip_bfloat16*)(WqT + 256 * 256);  // 256 KB
    __hip_bfloat16* WihT = WkvT + 512 * 256;                    // 3.1 MB
    __hip_bfloat16* WhhT = WihT + (size_t)768 * 2048;           // 384 KB
    __hip_bfloat16* resh_bf = WhhT + 768 * 256;                 // 2.1 MB
    __hip_bfloat16* pdbf = resh_bf + (size_t)BB * 2048;         // 256 KB
    float* gi = (float*)(pdbf + BB * 256);                      // 1.6 MB
    float* gh = gi + (size_t)BB * D3;                           // 1.6 MB
    int* idxb = (int*)(gh + (size_t)BB * D3);

    float* newd = out;                       // [B, D]
    float* resh = out + (size_t)BB * DD;     // [B, TOPK*D]

    k_xa    <<<(BB * SS) / 16, 256, 0, stream>>>(x_obs, a_prev, W1, b1, W2, b2, xa);
    k_prep  <<<192, 256, 0, stream>>>(Wqkv, WqT, WkvT);
    k_trbf  <<<(2048 / 32) * (768 / 32), 256, 0, stream>>>(W_ih, WihT, 2048, 768);
    k_trbf  <<<(256 / 32) * (768 / 32), 256, 0, stream>>>(W_hh, WhhT, 256, 768);
    k_pdcast<<<(BB * DD) / 1024, 256, 0, stream>>>(prev_d, pdbf);
    k_score <<<BB, 256, 0, stream>>>(xa, Wqkv, WqT, bqkv, idxb);
    k_kvmm  <<<BB * 4, 256, 0, stream>>>(xa, WkvT, bqkv, kbf, vbf);
    k_sel   <<<BB, 256, 0, stream>>>(xa, Wqkv, bqkv, kbf, vbf, Wo, bo, idxb, resh, resh_bf);
    k_gemm_bf<<<(512 / 128) * (768 / 128), 256, 0, stream>>>(resh_bf, WihT, gi, 2048, 768, 6);
    k_gemm_bf<<<(512 / 128) * (768 / 128), 256, 0, stream>>>(pdbf, WhhT, gh, 256, 768, 6);
    k_gruact<<<BB, 256, 0, stream>>>(gi, gh, b_ih, b_hh, prev_d, newd);
}

// Round 7
// 459.784 us; speedup vs baseline: 14.3261x; 1.1824x over previous
//
#include <hip/hip_runtime.h>
#include <hip/hip_bf16.h>
#include <math.h>

#define BB 512
#define SS 128
#define DD 256
#define HH 4
#define TOPK 8
#define D3 768
#define DMA 248
#define ACT_ 8
#define NTOK 65536            // B*S

typedef __attribute__((ext_vector_type(8))) short bf16x8;
typedef __attribute__((ext_vector_type(4))) short short4v;
typedef __attribute__((ext_vector_type(4))) float f32x4;

static __device__ __forceinline__ short f2bf(float x) {
    __hip_bfloat16 h = __float2bfloat16(x);
    return *reinterpret_cast<short*>(&h);
}
static __device__ __forceinline__ float bf2f(short s) {
    __hip_bfloat16 h = *reinterpret_cast<__hip_bfloat16*>(&s);
    return __bfloat162float(h);
}
static __device__ __forceinline__ float tanh_fast(float x) {
    float e = __expf(2.f * x);
    return 1.f - 2.f / (e + 1.f);
}

// ---------------------------------------------------------------------------
// K_xsplit: x_obs fp32 -> hi/lo bf16 (split-float). 4 elems/thread.
// ---------------------------------------------------------------------------
__global__ void k_xsplit(const float* __restrict__ src, short* __restrict__ hi,
                         short* __restrict__ lo) {
    int i = (blockIdx.x * 256 + threadIdx.x) * 4;
    float4 v = *(const float4*)&src[i];
    short4v h, l;
    h[0] = f2bf(v.x); l[0] = f2bf(v.x - bf2f(h[0]));
    h[1] = f2bf(v.y); l[1] = f2bf(v.y - bf2f(h[1]));
    h[2] = f2bf(v.z); l[2] = f2bf(v.z - bf2f(h[2]));
    h[3] = f2bf(v.w); l[3] = f2bf(v.w - bf2f(h[3]));
    *(short4v*)&hi[i] = h;
    *(short4v*)&lo[i] = l;
}

// ---------------------------------------------------------------------------
// K_wsplit_tr: src fp32 [R x C] -> hi/lo bf16 transposed [Cpad x R], zero pad.
// grid = (R/32)*(Cpad/32) blocks of 256.
// ---------------------------------------------------------------------------
__global__ void k_wsplit_tr(const float* __restrict__ src, short* __restrict__ dhi,
                            short* __restrict__ dlo, int R, int C, int Cpad) {
    __shared__ float t[32][33];
    const int ctiles = Cpad >> 5;
    const int rt = blockIdx.x / ctiles, ct = blockIdx.x % ctiles;
    const int r0 = rt * 32, c0 = ct * 32;
    const int tid = threadIdx.x;
#pragma unroll
    for (int i = 0; i < 4; ++i) {
        int idx = i * 256 + tid;
        int lr = idx >> 5, lc = idx & 31;
        t[lr][lc] = (c0 + lc < C) ? src[(size_t)(r0 + lr) * C + c0 + lc] : 0.f;
    }
    __syncthreads();
#pragma unroll
    for (int i = 0; i < 4; ++i) {
        int idx = i * 256 + tid;
        int lc = idx >> 5, lr = idx & 31;
        float v = t[lr][lc];
        short h = f2bf(v);
        size_t o = (size_t)(c0 + lc) * R + r0 + lr;
        dhi[o] = h;
        dlo[o] = f2bf(v - bf2f(h));
    }
}

// ---------------------------------------------------------------------------
// K_mlp1: h = tanh(x_obs @ W1 + b1), split-bf16 MFMA (3 passes), out hi/lo.
// Block: 64 tokens x 256 n; wave w = 64-col strip. K=64. No LDS (B L2-hot).
// ---------------------------------------------------------------------------
__global__ void __launch_bounds__(256) k_mlp1(const short* __restrict__ xhi,
        const short* __restrict__ xlo, const short* __restrict__ W1Thi,
        const short* __restrict__ W1Tlo, const float* __restrict__ b1,
        short* __restrict__ hhi, short* __restrict__ hlo) {
    const int m0 = blockIdx.x * 64;
    const int tid = threadIdx.x;
    const int wave = tid >> 6, lane = tid & 63;
    const int quad = lane >> 4, l15 = lane & 15;
    const int n0 = wave * 64;

    bf16x8 Bh[4][2], Bl[4][2];
#pragma unroll
    for (int nt = 0; nt < 4; ++nt)
#pragma unroll
        for (int ks = 0; ks < 2; ++ks) {
            size_t o = (size_t)(n0 + nt * 16 + l15) * 64 + ks * 32 + quad * 8;
            Bh[nt][ks] = *(const bf16x8*)&W1Thi[o];
            Bl[nt][ks] = *(const bf16x8*)&W1Tlo[o];
        }

    f32x4 acc[4][4];
#pragma unroll
    for (int mt = 0; mt < 4; ++mt)
#pragma unroll
        for (int nt = 0; nt < 4; ++nt) acc[mt][nt] = (f32x4){0.f, 0.f, 0.f, 0.f};

#pragma unroll
    for (int mt = 0; mt < 4; ++mt) {
        bf16x8 Ah[2], Al[2];
#pragma unroll
        for (int ks = 0; ks < 2; ++ks) {
            size_t o = (size_t)(m0 + mt * 16 + l15) * 64 + ks * 32 + quad * 8;
            Ah[ks] = *(const bf16x8*)&xhi[o];
            Al[ks] = *(const bf16x8*)&xlo[o];
        }
#pragma unroll
        for (int nt = 0; nt < 4; ++nt)
#pragma unroll
            for (int ks = 0; ks < 2; ++ks) {
                acc[mt][nt] = __builtin_amdgcn_mfma_f32_16x16x32_bf16(Ah[ks], Bh[nt][ks], acc[mt][nt], 0, 0, 0);
                acc[mt][nt] = __builtin_amdgcn_mfma_f32_16x16x32_bf16(Ah[ks], Bl[nt][ks], acc[mt][nt], 0, 0, 0);
                acc[mt][nt] = __builtin_amdgcn_mfma_f32_16x16x32_bf16(Al[ks], Bh[nt][ks], acc[mt][nt], 0, 0, 0);
            }
    }
#pragma unroll
    for (int nt = 0; nt < 4; ++nt) {
        int col = n0 + nt * 16 + l15;
        float bias = b1[col];
#pragma unroll
        for (int mt = 0; mt < 4; ++mt)
#pragma unroll
            for (int r = 0; r < 4; ++r) {
                int token = m0 + mt * 16 + quad * 4 + r;
                float t = tanh_fast(acc[mt][nt][r] + bias);
                short h = f2bf(t);
                size_t o = (size_t)token * 256 + col;
                hhi[o] = h;
                hlo[o] = f2bf(t - bf2f(h));
            }
    }
}

// ---------------------------------------------------------------------------
// K_mlp2: xa[:, :248] = h @ W2 + b2 (split-bf16 MFMA, K=256); xa[:,248:] = a_prev
// Block: 64 tokens x 256 n; wave = 64-col strip.
// ---------------------------------------------------------------------------
__global__ void __launch_bounds__(256) k_mlp2(const short* __restrict__ hhi,
        const short* __restrict__ hlo, const short* __restrict__ W2Thi,
        const short* __restrict__ W2Tlo, const float* __restrict__ b2,
        const float* __restrict__ a_prev, float* __restrict__ xa) {
    const int m0 = blockIdx.x * 64;
    const int tid = threadIdx.x;
    const int wave = tid >> 6, lane = tid & 63;
    const int quad = lane >> 4, l15 = lane & 15;
    const int n0 = wave * 64;

    f32x4 acc[4][4];
#pragma unroll
    for (int mt = 0; mt < 4; ++mt)
#pragma unroll
        for (int nt = 0; nt < 4; ++nt) acc[mt][nt] = (f32x4){0.f, 0.f, 0.f, 0.f};

    for (int k0 = 0; k0 < 256; k0 += 32) {
        bf16x8 Bh[4], Bl[4];
#pragma unroll
        for (int nt = 0; nt < 4; ++nt) {
            size_t o = (size_t)(n0 + nt * 16 + l15) * 256 + k0 + quad * 8;
            Bh[nt] = *(const bf16x8*)&W2Thi[o];
            Bl[nt] = *(const bf16x8*)&W2Tlo[o];
        }
#pragma unroll
        for (int mt = 0; mt < 4; ++mt) {
            size_t o = (size_t)(m0 + mt * 16 + l15) * 256 + k0 + quad * 8;
            bf16x8 Ah = *(const bf16x8*)&hhi[o];
            bf16x8 Al = *(const bf16x8*)&hlo[o];
#pragma unroll
            for (int nt = 0; nt < 4; ++nt) {
                acc[mt][nt] = __builtin_amdgcn_mfma_f32_16x16x32_bf16(Ah, Bh[nt], acc[mt][nt], 0, 0, 0);
                acc[mt][nt] = __builtin_amdgcn_mfma_f32_16x16x32_bf16(Ah, Bl[nt], acc[mt][nt], 0, 0, 0);
                acc[mt][nt] = __builtin_amdgcn_mfma_f32_16x16x32_bf16(Al, Bh[nt], acc[mt][nt], 0, 0, 0);
            }
        }
    }
#pragma unroll
    for (int nt = 0; nt < 4; ++nt) {
        int col = n0 + nt * 16 + l15;
        float bias = (col < DMA) ? b2[col] : 0.f;
#pragma unroll
        for (int mt = 0; mt < 4; ++mt)
#pragma unroll
            for (int r = 0; r < 4; ++r) {
                int token = m0 + mt * 16 + quad * 4 + r;
                float v;
                if (col < DMA) v = acc[mt][nt][r] + bias;
                else           v = a_prev[(size_t)token * ACT_ + (col - DMA)];
                xa[(size_t)token * 256 + col] = v;
            }
    }
}

// ---------------------------------------------------------------------------
// K_prep: WqT fp32 [256x256] transpose; WkvT bf16 [512x256]. 192 blocks.
// ---------------------------------------------------------------------------
__global__ void k_prep(const float* __restrict__ Wqkv, float* __restrict__ WqT,
                       __hip_bfloat16* __restrict__ WkvT) {
    __shared__ float t[32][33];
    const int rt = blockIdx.x / 24, ct = blockIdx.x % 24;
    const int r0 = rt * 32, c0 = ct * 32;
    const int tid = threadIdx.x;
#pragma unroll
    for (int i = 0; i < 4; ++i) {
        int idx = i * 256 + tid;
        int lr = idx >> 5, lc = idx & 31;
        t[lr][lc] = Wqkv[(size_t)(r0 + lr) * D3 + c0 + lc];
    }
    __syncthreads();
#pragma unroll
    for (int i = 0; i < 4; ++i) {
        int idx = i * 256 + tid;
        int lc = idx >> 5, lr = idx & 31;
        float v = t[lr][lc];
        int c = c0 + lc, r = r0 + lr;
        if (c < 256) WqT[(size_t)c * 256 + r] = v;
        else         WkvT[(size_t)(c - 256) * 256 + r] = __float2bfloat16(v);
    }
}

// ---------------------------------------------------------------------------
// K_trbf: generic fp32 [R x C] -> bf16 transposed [C x R]. 32x32 tiles.
// ---------------------------------------------------------------------------
__global__ void k_trbf(const float* __restrict__ src, __hip_bfloat16* __restrict__ dst,
                       int R, int C) {
    __shared__ float t[32][33];
    const int ctiles = C >> 5;
    const int rt = blockIdx.x / ctiles, ct = blockIdx.x % ctiles;
    const int r0 = rt * 32, c0 = ct * 32;
    const int tid = threadIdx.x;
#pragma unroll
    for (int i = 0; i < 4; ++i) {
        int idx = i * 256 + tid;
        int lr = idx >> 5, lc = idx & 31;
        t[lr][lc] = src[(size_t)(r0 + lr) * C + c0 + lc];
    }
    __syncthreads();
#pragma unroll
    for (int i = 0; i < 4; ++i) {
        int idx = i * 256 + tid;
        int lc = idx >> 5, lr = idx & 31;
        dst[(size_t)(c0 + lc) * R + r0 + lr] = __float2bfloat16(t[lr][lc]);
    }
}

// ---------------------------------------------------------------------------
// K_pdcast: prev_d fp32 -> bf16
// ---------------------------------------------------------------------------
__global__ void k_pdcast(const float* __restrict__ src, __hip_bfloat16* __restrict__ dst) {
    int i = blockIdx.x * 1024 + threadIdx.x * 4;
    float4 v = *(const float4*)&src[i];
    dst[i]     = __float2bfloat16(v.x);
    dst[i + 1] = __float2bfloat16(v.y);
    dst[i + 2] = __float2bfloat16(v.z);
    dst[i + 3] = __float2bfloat16(v.w);
}

// ---------------------------------------------------------------------------
// K2: per batch: xasum -> ksum -> wqk -> fp64 score rows -> wave top-8.
// ---------------------------------------------------------------------------
__global__ void __launch_bounds__(256) k_score(const float* __restrict__ xa,
        const float* __restrict__ Wqkv, const float* __restrict__ WqT,
        const float* __restrict__ bqkv, int* __restrict__ idxb) {
    __shared__ float xasum_sh[256];
    __shared__ float ksum_sh[256];
    __shared__ float wqk_sh[256];
    __shared__ double ssd[128];
    const int b = blockIdx.x;
    const int tid = threadIdx.x;
    const float* xab = xa + (size_t)b * SS * DD;

    float s = 0.f;
    for (int r = 0; r < 128; ++r) s += xab[r * 256 + tid];
    xasum_sh[tid] = s;
    __syncthreads();

    float ks = 128.f * bqkv[256 + tid];
    for (int d = 0; d < 256; ++d)
        ks = fmaf(xasum_sh[d], Wqkv[(size_t)d * D3 + 256 + tid], ks);
    ksum_sh[tid] = ks;
    __syncthreads();

    float wq = 0.f;
    for (int c = 0; c < 256; ++c)
        wq = fmaf(WqT[(size_t)c * 256 + tid], ksum_sh[c], wq);
    wqk_sh[tid] = wq;
    double bqdot = 0.0;
    for (int c = 0; c < 256; ++c)
        bqdot += (double)bqkv[c] * (double)ksum_sh[c];
    __syncthreads();

    {
        int r = tid >> 1, half = tid & 1;
        const float* xr = xab + (size_t)r * 256 + half * 128;
        const float* wk = wqk_sh + half * 128;
        double sd = 0.0;
        for (int d2 = 0; d2 < 128; ++d2) sd += (double)xr[d2] * (double)wk[d2];
        double so = __shfl_xor(sd, 1);
        if (half == 0) ssd[r] = (sd + so + bqdot) * 0.125;
    }
    __syncthreads();
    if (tid < 64) {
        double v0 = ssd[tid], v1 = ssd[tid + 64];
        int i0 = tid, i1 = tid + 64;
        bool t0 = false, t1 = false;
        for (int t = 0; t < TOPK; ++t) {
            double c0 = t0 ? -1e300 : v0;
            double c1 = t1 ? -1e300 : v1;
            double bvv; int bi;
            if (c1 > c0) { bvv = c1; bi = i1; } else { bvv = c0; bi = i0; }
#pragma unroll
            for (int off = 1; off < 64; off <<= 1) {
                double ov = __shfl_xor(bvv, off);
                int oi = __shfl_xor(bi, off);
                if (ov > bvv || (ov == bvv && oi < bi)) { bvv = ov; bi = oi; }
            }
            if (tid == 0) idxb[b * TOPK + t] = bi;
            if (bi == i0) t0 = true;
            if (bi == i1) t1 = true;
        }
    }
}

// ---------------------------------------------------------------------------
// K3: bf16 MFMA K/V GEMM (test-verified fragment pattern)
// ---------------------------------------------------------------------------
__global__ void __launch_bounds__(256) k_kvmm(const float* __restrict__ xa,
        const __hip_bfloat16* __restrict__ WkvT, const float* __restrict__ bqkv,
        __hip_bfloat16* __restrict__ kbf, __hip_bfloat16* __restrict__ vbf) {
    __shared__ short Ash[128 * 36];
    __shared__ short Bsh[128 * 36];
    const int b = blockIdx.x >> 2, ntile = blockIdx.x & 3;
    const int tid = threadIdx.x;
    const int wave = tid >> 6, lane = tid & 63;
    const int wm = wave >> 1, wn = wave & 1;
    const int quad = lane >> 4, l15 = lane & 15;
    const float* xab = xa + (size_t)b * SS * DD;

    f32x4 acc[4][4];
#pragma unroll
    for (int tn = 0; tn < 4; ++tn) {
        int n_g = ntile * 128 + wn * 64 + tn * 16 + l15;
        float bias = bqkv[256 + n_g];
#pragma unroll
        for (int tm = 0; tm < 4; ++tm)
            acc[tm][tn] = (f32x4){bias, bias, bias, bias};
    }

    for (int k0 = 0; k0 < 256; k0 += 32) {
        __syncthreads();
#pragma unroll
        for (int it = 0; it < 4; ++it) {
            int idx = it * 256 + tid;
            int row = idx >> 3, f4 = idx & 7;
            float4 x4 = *(const float4*)&xab[(size_t)row * 256 + k0 + f4 * 4];
            short4v sv = { f2bf(x4.x), f2bf(x4.y), f2bf(x4.z), f2bf(x4.w) };
            *(short4v*)&Ash[row * 36 + f4 * 4] = sv;
        }
#pragma unroll
        for (int it = 0; it < 2; ++it) {
            int idx = it * 256 + tid;
            int nr = idx >> 2, q4 = idx & 3;
            uint4 w = *(const uint4*)&WkvT[((size_t)(ntile * 128 + nr)) * 256 + k0 + q4 * 8];
            *(short4v*)&Bsh[nr * 36 + q4 * 8]     = ((short4v*)&w)[0];
            *(short4v*)&Bsh[nr * 36 + q4 * 8 + 4] = ((short4v*)&w)[1];
        }
        __syncthreads();

        bf16x8 af[4], bfr[4];
#pragma unroll
        for (int t = 0; t < 4; ++t) {
            int ar = (wm * 64 + t * 16 + l15) * 36 + quad * 8;
            short4v lo = *(short4v*)&Ash[ar];
            short4v hi = *(short4v*)&Ash[ar + 4];
            bf16x8 f;
            f[0]=lo[0]; f[1]=lo[1]; f[2]=lo[2]; f[3]=lo[3];
            f[4]=hi[0]; f[5]=hi[1]; f[6]=hi[2]; f[7]=hi[3];
            af[t] = f;
            int br = (wn * 64 + t * 16 + l15) * 36 + quad * 8;
            short4v blo = *(short4v*)&Bsh[br];
            short4v bhi = *(short4v*)&Bsh[br + 4];
            bf16x8 g;
            g[0]=blo[0]; g[1]=blo[1]; g[2]=blo[2]; g[3]=blo[3];
            g[4]=bhi[0]; g[5]=bhi[1]; g[6]=bhi[2]; g[7]=bhi[3];
            bfr[t] = g;
        }
#pragma unroll
        for (int tm = 0; tm < 4; ++tm)
#pragma unroll
            for (int tn = 0; tn < 4; ++tn)
                acc[tm][tn] = __builtin_amdgcn_mfma_f32_16x16x32_bf16(
                    af[tm], bfr[tn], acc[tm][tn], 0, 0, 0);
    }
#pragma unroll
    for (int tn = 0; tn < 4; ++tn) {
        int n_g = ntile * 128 + wn * 64 + tn * 16 + l15;
        __hip_bfloat16* dst = (n_g < 256) ? kbf : vbf;
        int nc = n_g & 255;
#pragma unroll
        for (int tm = 0; tm < 4; ++tm) {
#pragma unroll
            for (int r = 0; r < 4; ++r) {
                int token = wm * 64 + tm * 16 + quad * 4 + r;
                dst[((size_t)b * SS + token) * 256 + nc] = __float2bfloat16(acc[tm][tn][r]);
            }
        }
    }
}

// ---------------------------------------------------------------------------
// K_gemm_bf: C[M x N] fp32 = A_bf[M x K] @ BT_bf[N x K]^T. 128x128 tile, BK=64.
// ---------------------------------------------------------------------------
__global__ void __launch_bounds__(256) k_gemm_bf(const __hip_bfloat16* __restrict__ A,
        const __hip_bfloat16* __restrict__ BT, float* __restrict__ C,
        int K, int N, int ntiles) {
    __shared__ __attribute__((aligned(16))) short Ash[128 * 72];
    __shared__ __attribute__((aligned(16))) short Bsh[128 * 72];
    const int mt = blockIdx.x / ntiles, nt = blockIdx.x % ntiles;
    const int m0 = mt * 128, n0 = nt * 128;
    const int tid = threadIdx.x;
    const int wave = tid >> 6, lane = tid & 63;
    const int wm = wave >> 1, wn = wave & 1;
    const int quad = lane >> 4, l15 = lane & 15;

    f32x4 acc[4][4];
#pragma unroll
    for (int tm = 0; tm < 4; ++tm)
#pragma unroll
        for (int tn = 0; tn < 4; ++tn)
            acc[tm][tn] = (f32x4){0.f, 0.f, 0.f, 0.f};

    for (int k0 = 0; k0 < K; k0 += 64) {
        __syncthreads();
#pragma unroll
        for (int it = 0; it < 4; ++it) {
            int idx = it * 256 + tid;
            int row = idx >> 3, c8 = idx & 7;
            *(uint4*)&Ash[row * 72 + c8 * 8] =
                *(const uint4*)&A[(size_t)(m0 + row) * K + k0 + c8 * 8];
            *(uint4*)&Bsh[row * 72 + c8 * 8] =
                *(const uint4*)&BT[(size_t)(n0 + row) * K + k0 + c8 * 8];
        }
        __syncthreads();
#pragma unroll
        for (int ks = 0; ks < 2; ++ks) {
            bf16x8 af[4], bfr[4];
#pragma unroll
            for (int t = 0; t < 4; ++t) {
                af[t]  = *(bf16x8*)&Ash[(wm * 64 + t * 16 + l15) * 72 + ks * 32 + quad * 8];
                bfr[t] = *(bf16x8*)&Bsh[(wn * 64 + t * 16 + l15) * 72 + ks * 32 + quad * 8];
            }
#pragma unroll
            for (int tm = 0; tm < 4; ++tm)
#pragma unroll
                for (int tn = 0; tn < 4; ++tn)
                    acc[tm][tn] = __builtin_amdgcn_mfma_f32_16x16x32_bf16(
                        af[tm], bfr[tn], acc[tm][tn], 0, 0, 0);
        }
    }
#pragma unroll
    for (int tm = 0; tm < 4; ++tm)
#pragma unroll
        for (int tn = 0; tn < 4; ++tn) {
            int col = n0 + wn * 64 + tn * 16 + l15;
#pragma unroll
            for (int r = 0; r < 4; ++r) {
                int row = m0 + wm * 64 + tm * 16 + quad * 4 + r;
                C[(size_t)row * N + col] = acc[tm][tn][r];
            }
        }
}

// ---------------------------------------------------------------------------
// K_gruact: gates elementwise. newd = (1-z)*n + z*prev_d
// ---------------------------------------------------------------------------
__global__ void k_gruact(const float* __restrict__ gi, const float* __restrict__ gh,
                         const float* __restrict__ b_ih, const float* __restrict__ b_hh,
                         const float* __restrict__ prev_d, float* __restrict__ newd) {
    const int b = blockIdx.x, tid = threadIdx.x;
    const float* gib = gi + (size_t)b * D3;
    const float* ghb = gh + (size_t)b * D3;
    float ir = gib[tid] + b_ih[tid];
    float iz = gib[256 + tid] + b_ih[256 + tid];
    float in = gib[512 + tid] + b_ih[512 + tid];
    float hr = ghb[tid] + b_hh[tid];
    float hz = ghb[256 + tid] + b_hh[256 + tid];
    float hn = ghb[512 + tid] + b_hh[512 + tid];
    float pd = prev_d[(size_t)b * 256 + tid];
    float r = 1.f / (1.f + __expf(-(ir + hr)));
    float z = 1.f / (1.f + __expf(-(iz + hz)));
    float n = tanhf(in + r * hn);
    newd[(size_t)b * 256 + tid] = (1.f - z) * n + z * pd;
}

// ---------------------------------------------------------------------------
// K4: per b: recompute q for the 8 selected rows, per-head softmax(q·k)·v,
//     Wo + bo -> reshaped rows into d_out (fp32) + resh_bf (bf16) for GRU.
// ---------------------------------------------------------------------------
__global__ void __launch_bounds__(256) k_sel(const float* __restrict__ xa,
        const float* __restrict__ Wqkv, const float* __restrict__ bqkv,
        const __hip_bfloat16* __restrict__ kbf, const __hip_bfloat16* __restrict__ vbf,
        const float* __restrict__ Wo, const float* __restrict__ bo,
        const int* __restrict__ idxb, float* __restrict__ resh_out,
        __hip_bfloat16* __restrict__ resh_bf) {
    __shared__ float xsel[8][256];
    __shared__ float qsel[8][256];
    __shared__ __hip_bfloat16 ksh[128][66];
    __shared__ __hip_bfloat16 vsh[128][66];
    __shared__ float sbuf[8][128];
    __shared__ float ctxh[8][64];
    __shared__ int sidx[8];
    const int b = blockIdx.x;
    const int tid = threadIdx.x;
    const float* xab = xa + (size_t)b * SS * DD;

    if (tid < 8) sidx[tid] = idxb[b * TOPK + tid];
    __syncthreads();
#pragma unroll
    for (int t = 0; t < 8; ++t) xsel[t][tid] = xab[(size_t)sidx[t] * 256 + tid];
    __syncthreads();
    {
        float a[8];
        float bq = bqkv[tid];
#pragma unroll
        for (int t = 0; t < 8; ++t) a[t] = bq;
        for (int kk = 0; kk < 256; ++kk) {
            float w = Wqkv[(size_t)kk * D3 + tid];
#pragma unroll
            for (int t = 0; t < 8; ++t) a[t] = fmaf(xsel[t][kk], w, a[t]);
        }
#pragma unroll
        for (int t = 0; t < 8; ++t) qsel[t][tid] = a[t];
    }
    float racc[8];
#pragma unroll
    for (int r = 0; r < 8; ++r) racc[r] = 0.f;

    for (int h = 0; h < 4; ++h) {
        __syncthreads();
        for (int it = 0; it < 32; ++it) {
            int id = it * 256 + tid;
            int row = id >> 6, col = id & 63;
            size_t g = ((size_t)b * SS + row) * 256 + h * 64 + col;
            ksh[row][col] = kbf[g];
            vsh[row][col] = vbf[g];
        }
        __syncthreads();
#pragma unroll
        for (int j = 0; j < 4; ++j) {
            int id = j * 256 + tid;
            int row = id >> 7, col = id & 127;
            float s = 0.f;
            for (int d = 0; d < 64; ++d)
                s = fmaf(qsel[row][h * 64 + d], __bfloat162float(ksh[col][d]), s);
            sbuf[row][col] = s * 0.125f;
        }
        __syncthreads();
        if (tid < 8) {
            float m = -3.4e38f;
            for (int k2 = 0; k2 < 128; ++k2) m = fmaxf(m, sbuf[tid][k2]);
            float ssum = 0.f;
            for (int k2 = 0; k2 < 128; ++k2) {
                float e = __expf(sbuf[tid][k2] - m);
                sbuf[tid][k2] = e;
                ssum += e;
            }
            float inv = 1.f / ssum;
            for (int k2 = 0; k2 < 128; ++k2) sbuf[tid][k2] *= inv;
        }
        __syncthreads();
#pragma unroll
        for (int j = 0; j < 2; ++j) {
            int id = j * 256 + tid;
            int row = id >> 6, col = id & 63;
            float c = 0.f;
            for (int k2 = 0; k2 < 128; ++k2)
                c = fmaf(sbuf[row][k2], __bfloat162float(vsh[k2][col]), c);
            ctxh[row][col] = c;
        }
        __syncthreads();
        for (int jj = 0; jj < 64; ++jj) {
            float w = Wo[(size_t)(h * 64 + jj) * 256 + tid];
#pragma unroll
            for (int r = 0; r < 8; ++r) racc[r] = fmaf(ctxh[r][jj], w, racc[r]);
        }
    }
    float bov = bo[tid];
#pragma unroll
    for (int r = 0; r < 8; ++r) {
        float v = racc[r] + bov;
        resh_out[(size_t)b * 2048 + r * 256 + tid] = v;
        resh_bf[(size_t)b * 2048 + r * 256 + tid] = __float2bfloat16(v);
    }
}

// ---------------------------------------------------------------------------
extern "C" void kernel_launch(void* const* d_in, const int* in_sizes, int n_in,
                              void* d_out, int out_size, void* d_ws, size_t ws_size,
                              hipStream_t stream) {
    const float* prev_d = (const float*)d_in[0];
    const float* x_obs  = (const float*)d_in[1];
    const float* a_prev = (const float*)d_in[2];
    const float* W1     = (const float*)d_in[3];
    const float* b1     = (const float*)d_in[4];
    const float* W2     = (const float*)d_in[5];
    const float* b2     = (const float*)d_in[6];
    const float* Wqkv   = (const float*)d_in[7];
    const float* bqkv   = (const float*)d_in[8];
    const float* Wo     = (const float*)d_in[9];
    const float* bo     = (const float*)d_in[10];
    const float* W_ih   = (const float*)d_in[11];
    const float* b_ih   = (const float*)d_in[12];
    const float* W_hh   = (const float*)d_in[13];
    const float* b_hh   = (const float*)d_in[14];
    float* out = (float*)d_out;

    const size_t NT = (size_t)BB * SS * DD;   // 16,777,216
    // region 1: xa fp32 (67 MB)
    float* xa = (float*)d_ws;
    // region 2 (67 MB, dual use): [hhi|hlo] during MLP, then [kbf|vbf]
    short* hkv = (short*)(xa + NT);
    short* hhi = hkv;
    short* hlo = hkv + NT;
    __hip_bfloat16* kbf = (__hip_bfloat16*)hkv;
    __hip_bfloat16* vbf = (__hip_bfloat16*)(hkv + NT);
    // region 3 (16.8 MB, dual use): [xhi|xlo] during MLP1, then late buffers
    short* xsp = hkv + 2 * NT;
    short* xhi = xsp;
    short* xlo = xsp + (size_t)NTOK * 64;
    char* late = (char*)xsp;
    __hip_bfloat16* WihT = (__hip_bfloat16*)late;                     // 3,145,728 B
    __hip_bfloat16* WhhT = (__hip_bfloat16*)(late + 3145728);         // 393,216 B
    __hip_bfloat16* resh_bf = (__hip_bfloat16*)(late + 3538944);      // 2,097,152 B
    __hip_bfloat16* pdbf = (__hip_bfloat16*)(late + 5636096);         // 262,144 B
    float* gi = (float*)(late + 5898240);                             // 1,572,864 B
    float* gh = (float*)(late + 7471104);                             // 1,572,864 B
    // region 4: persistent small
    short* fixed = xsp + 2 * (size_t)NTOK * 64;
    short* W1Thi = fixed;                    // 16384
    short* W1Tlo = W1Thi + 16384;
    short* W2Thi = W1Tlo + 16384;            // 65536
    short* W2Tlo = W2Thi + 65536;
    float* WqT = (float*)(W2Tlo + 65536);    // 65536 floats
    __hip_bfloat16* WkvT = (__hip_bfloat16*)(WqT + 65536);  // 131072
    int* idxb = (int*)(WkvT + 131072);

    float* newd = out;                       // [B, D]
    float* resh = out + (size_t)BB * DD;     // [B, TOPK*D]

    // MLP (split-bf16 MFMA)
    k_xsplit  <<<(NTOK * 64) / 1024, 256, 0, stream>>>(x_obs, xhi, xlo);
    k_wsplit_tr<<<(64 / 32) * (256 / 32), 256, 0, stream>>>(W1, W1Thi, W1Tlo, 64, 256, 256);
    k_wsplit_tr<<<(256 / 32) * (256 / 32), 256, 0, stream>>>(W2, W2Thi, W2Tlo, 256, DMA, 256);
    k_mlp1    <<<NTOK / 64, 256, 0, stream>>>(xhi, xlo, W1Thi, W1Tlo, b1, hhi, hlo);
    k_mlp2    <<<NTOK / 64, 256, 0, stream>>>(hhi, hlo, W2Thi, W2Tlo, b2, a_prev, xa);
    // attention + topk (h region is now dead; late region overwrites xsplit)
    k_prep    <<<192, 256, 0, stream>>>(Wqkv, WqT, WkvT);
    k_trbf    <<<(2048 / 32) * (768 / 32), 256, 0, stream>>>(W_ih, WihT, 2048, 768);
    k_trbf    <<<(256 / 32) * (768 / 32), 256, 0, stream>>>(W_hh, WhhT, 256, 768);
    k_pdcast  <<<(BB * DD) / 1024, 256, 0, stream>>>(prev_d, pdbf);
    k_score   <<<BB, 256, 0, stream>>>(xa, Wqkv, WqT, bqkv, idxb);
    k_kvmm    <<<BB * 4, 256, 0, stream>>>(xa, WkvT, bqkv, kbf, vbf);
    k_sel     <<<BB, 256, 0, stream>>>(xa, Wqkv, bqkv, kbf, vbf, Wo, bo, idxb, resh, resh_bf);
    k_gemm_bf <<<(512 / 128) * (768 / 128), 256, 0, stream>>>(resh_bf, WihT, gi, 2048, 768, 6);
    k_gemm_bf <<<(512 / 128) * (768 / 128), 256, 0, stream>>>(pdbf, WhhT, gh, 256, 768, 6);
    k_gruact  <<<BB, 256, 0, stream>>>(gi, gh, b_ih, b_hh, prev_d, newd);
}